// Round 10
// baseline (2096.080 us; speedup 1.0000x reference)
//
#include <hip/hip_runtime.h>

using short8v = __attribute__((ext_vector_type(8))) short;
using float4v = __attribute__((ext_vector_type(4))) float;

__device__ __forceinline__ unsigned short f2bf(float f) {
  unsigned int u = __float_as_uint(f);
  u += 0x7FFF + ((u >> 16) & 1);
  return (unsigned short)(u >> 16);
}
__device__ __forceinline__ float bf2f(unsigned short u) {
  return __uint_as_float((unsigned int)u << 16);
}

__device__ __forceinline__ int swz(int row, int c) {
  return row * 64 + (c ^ ((row & 7) << 3));
}

// ------------------------------------------------------------------
// bf16 MFMA GEMM, reg-staged + prefetch + LDS XOR swizzle.
// C = act(alpha*A.B^T + bias + resid). BM in {128, 64}. K % 64 == 0.
// RES: 0 none, 1 bf16 resid, 2 f32 resid.
// VT: cols >= 1536 (rows < vmax) are written TRANSPOSED per-group:
//     vtp[(row/vrows)*98304 + (col-1536)*128 + row%vrows], not to C.
// ------------------------------------------------------------------
template<int BM, int ACT, bool OUTBF, int RES, int VT>
__global__ __launch_bounds__(256) void gemm_mfma(
    const unsigned short* __restrict__ A, const unsigned short* __restrict__ B,
    const float* __restrict__ bias, const void* __restrict__ resid, int ldr,
    void* __restrict__ Cv, unsigned short* __restrict__ vtp, int vrows, int vmax,
    int M, int N, int K, int lda, int ldb, int ldc,
    long long sA, long long sB, long long sC, long long sBias, float alpha)
{
  constexpr int NF = BM / 32;
  A += (long long)blockIdx.z * sA;
  B += (long long)blockIdx.z * sB;
  if (bias) bias += (long long)blockIdx.z * sBias;
  const int m0 = blockIdx.y * BM, n0 = blockIdx.x * BM;

  __shared__ __align__(16) unsigned short As[BM * 64];
  __shared__ __align__(16) unsigned short Bs[BM * 64];

  const int tid = threadIdx.x;
  const int w = tid >> 6, lane = tid & 63;
  const int wr = w >> 1, wc = w & 1;

  const int r0 = tid >> 3;
  const int c8 = (tid & 7) * 8;
  int ra[NF], rb[NF], soff[NF];
  #pragma unroll
  for (int i = 0; i < NF; ++i) {
    int r = m0 + r0 + i * 32; ra[i] = r < M - 1 ? r : M - 1;
    int q = n0 + r0 + i * 32; rb[i] = q < N - 1 ? q : N - 1;
    soff[i] = swz(r0 + i * 32, c8);
  }

  const int fr = lane & 15;
  const int fk = (lane >> 4) * 8;

  float4v acc[NF][NF] = {};

  short8v pa[NF], pb[NF];
  #pragma unroll
  for (int i = 0; i < NF; ++i) {
    pa[i] = *(const short8v*)(A + (long long)ra[i] * lda + c8);
    pb[i] = *(const short8v*)(B + (long long)rb[i] * ldb + c8);
  }

  for (int k0 = 0; k0 < K; k0 += 64) {
    __syncthreads();
    #pragma unroll
    for (int i = 0; i < NF; ++i) {
      *(short8v*)&As[soff[i]] = pa[i];
      *(short8v*)&Bs[soff[i]] = pb[i];
    }
    __syncthreads();
    if (k0 + 64 < K) {
      #pragma unroll
      for (int i = 0; i < NF; ++i) {
        pa[i] = *(const short8v*)(A + (long long)ra[i] * lda + k0 + 64 + c8);
        pb[i] = *(const short8v*)(B + (long long)rb[i] * ldb + k0 + 64 + c8);
      }
    }
    #pragma unroll
    for (int kk = 0; kk < 2; ++kk) {
      short8v a[NF], b[NF];
      #pragma unroll
      for (int i = 0; i < NF; ++i) {
        a[i] = *(const short8v*)&As[swz(wr * (NF * 16) + i * 16 + fr, kk * 32 + fk)];
        b[i] = *(const short8v*)&Bs[swz(wc * (NF * 16) + i * 16 + fr, kk * 32 + fk)];
      }
      #pragma unroll
      for (int mi = 0; mi < NF; ++mi)
        #pragma unroll
        for (int ni = 0; ni < NF; ++ni)
          acc[mi][ni] = __builtin_amdgcn_mfma_f32_16x16x32_bf16(a[mi], b[ni], acc[mi][ni], 0, 0, 0);
    }
  }

  const int ccol0 = n0 + wc * (NF * 16) + (lane & 15);
  const int crow0 = m0 + wr * (NF * 16) + (lane >> 4) * 4;
  float* Cf = (float*)Cv + (long long)blockIdx.z * sC;
  unsigned short* Cb = (unsigned short*)Cv + (long long)blockIdx.z * sC;
  #pragma unroll
  for (int ni = 0; ni < NF; ++ni) {
    const int col = ccol0 + ni * 16;
    if (col >= N) continue;
    const float bs = bias ? bias[col] : 0.f;
    #pragma unroll
    for (int mi = 0; mi < NF; ++mi) {
      #pragma unroll
      for (int r = 0; r < 4; ++r) {
        const int row = crow0 + mi * 16 + r;
        if (row >= M) continue;
        float v = acc[mi][ni][r] * alpha + bs;
        if (RES == 1) v += bf2f(((const unsigned short*)resid)[(long long)row * ldr + col]);
        if (RES == 2) v += ((const float*)resid)[(long long)row * ldr + col];
        if (ACT == 1) v = fmaxf(v, 0.f);
        if (ACT == 2) v = 0.5f * v * (1.f + erff(v * 0.70710678118654752f));
        if (VT && col >= 1536) {
          if (row < vmax) {
            const int bq = row / vrows;
            const int kk2 = row - bq * vrows;
            vtp[(long long)bq * 98304 + (long long)(col - 1536) * 128 + kk2] = f2bf(v);
          }
        } else if (OUTBF) {
          Cb[(long long)row * ldc + col] = f2bf(v);
        } else {
          Cf[(long long)row * ldc + col] = v;
        }
      }
    }
  }
}

static void mg(hipStream_t st, int bm, int act, bool outbf, int res,
               const unsigned short* A, const unsigned short* B,
               const float* bias, const void* resid, int ldr, void* C,
               unsigned short* vtp, int vrows, int vmax,
               int M, int N, int K, int lda, int ldb, int ldc,
               long long sA, long long sB, long long sC, long long sBias,
               int bat, float alpha)
{
  dim3 grid((N + bm - 1) / bm, (M + bm - 1) / bm, bat);
  dim3 blk(256);
  #define GEMM_CALL(BM_, A_, O_, R_, V_) \
    gemm_mfma<BM_, A_, O_, R_, V_><<<grid, blk, 0, st>>>(A, B, bias, resid, ldr, C, \
        vtp, vrows, vmax, M, N, K, lda, ldb, ldc, sA, sB, sC, sBias, alpha)
  if (bm == 128) {
    if (outbf) {
      if (act == 1)       GEMM_CALL(128, 1, true, 0, 0);
      else if (res == 1)  GEMM_CALL(128, 0, true, 1, 0);
      else if (vtp)       GEMM_CALL(128, 0, true, 0, 1);
      else                GEMM_CALL(128, 0, true, 0, 0);
    } else {
      GEMM_CALL(128, 0, false, 0, 0);
    }
  } else {
    if (outbf) {
      if (act == 2)       GEMM_CALL(64, 2, true, 0, 0);
      else if (vtp)       GEMM_CALL(64, 0, true, 0, 1);
      else                GEMM_CALL(64, 0, true, 0, 0);
    } else {
      if (res == 2)       GEMM_CALL(64, 0, false, 2, 0);
      else                GEMM_CALL(64, 0, false, 0, 0);
    }
  }
  #undef GEMM_CALL
}

// ------------------------------------------------------------------
// fused score + softmax: P = softmax(Q.K^T * alpha) -> bf16 [128][128]
// One block per sequence (full rows in-register). Valid cols < Mv.
// ------------------------------------------------------------------
__global__ __launch_bounds__(256) void scoresm_kernel(
    const unsigned short* __restrict__ Q, const unsigned short* __restrict__ Kp,
    unsigned short* __restrict__ P,
    int Mv, int K, int lda, long long sQ, long long sP, float alpha)
{
  const int z = blockIdx.z;
  Q  += (long long)z * sQ;
  Kp += (long long)z * sQ;
  P  += (long long)z * sP;

  __shared__ __align__(16) unsigned short As[128 * 64];
  __shared__ __align__(16) unsigned short Bs[128 * 64];
  float* ovl = (float*)As;          // overlay after phase 1: [0..255] max, [256..511] sum

  const int tid = threadIdx.x;
  const int w = tid >> 6, lane = tid & 63;
  const int wr = w >> 1, wc = w & 1;
  const int r0 = tid >> 3, c8 = (tid & 7) * 8;

  int ra[4], soff[4];
  #pragma unroll
  for (int i = 0; i < 4; ++i) {
    int r = r0 + i * 32;
    ra[i] = (r < Mv - 1 ? r : Mv - 1);
    soff[i] = swz(r, c8);
  }
  const int fr = lane & 15, fk = (lane >> 4) * 8;

  float4v acc[4][4] = {};
  short8v pa[4], pb[4];
  #pragma unroll
  for (int i = 0; i < 4; ++i) {
    pa[i] = *(const short8v*)(Q  + (long long)ra[i] * lda + c8);
    pb[i] = *(const short8v*)(Kp + (long long)ra[i] * lda + c8);
  }
  for (int k0 = 0; k0 < K; k0 += 64) {
    __syncthreads();
    #pragma unroll
    for (int i = 0; i < 4; ++i) {
      *(short8v*)&As[soff[i]] = pa[i];
      *(short8v*)&Bs[soff[i]] = pb[i];
    }
    __syncthreads();
    if (k0 + 64 < K) {
      #pragma unroll
      for (int i = 0; i < 4; ++i) {
        pa[i] = *(const short8v*)(Q  + (long long)ra[i] * lda + k0 + 64 + c8);
        pb[i] = *(const short8v*)(Kp + (long long)ra[i] * lda + k0 + 64 + c8);
      }
    }
    #pragma unroll
    for (int kk = 0; kk < 2; ++kk) {
      short8v a[4], b[4];
      #pragma unroll
      for (int i = 0; i < 4; ++i) {
        a[i] = *(const short8v*)&As[swz(wr * 64 + i * 16 + fr, kk * 32 + fk)];
        b[i] = *(const short8v*)&Bs[swz(wc * 64 + i * 16 + fr, kk * 32 + fk)];
      }
      #pragma unroll
      for (int mi = 0; mi < 4; ++mi)
        #pragma unroll
        for (int ni = 0; ni < 4; ++ni)
          acc[mi][ni] = __builtin_amdgcn_mfma_f32_16x16x32_bf16(a[mi], b[ni], acc[mi][ni], 0, 0, 0);
    }
  }
  __syncthreads();                  // As reads done -> overlay safe

  const int g = lane >> 4, f = lane & 15;
  const int colB = wc * 64 + f;
  const int rowB = wr * 64 + g * 4;

  bool cv[4];
  #pragma unroll
  for (int ni = 0; ni < 4; ++ni) cv[ni] = (colB + ni * 16) < Mv;

  float lm[4][4];
  #pragma unroll
  for (int mi = 0; mi < 4; ++mi) {
    #pragma unroll
    for (int r = 0; r < 4; ++r) {
      float mx = -3.4e38f;
      #pragma unroll
      for (int ni = 0; ni < 4; ++ni) {
        float v = cv[ni] ? acc[mi][ni][r] * alpha : -3.4e38f;
        acc[mi][ni][r] = v;
        mx = fmaxf(mx, v);
      }
      #pragma unroll
      for (int off = 1; off < 16; off <<= 1) mx = fmaxf(mx, __shfl_xor(mx, off, 64));
      lm[mi][r] = mx;
    }
  }
  if (f == 0) {
    #pragma unroll
    for (int mi = 0; mi < 4; ++mi)
      #pragma unroll
      for (int r = 0; r < 4; ++r)
        ovl[wc * 128 + rowB + mi * 16 + r] = lm[mi][r];
  }
  __syncthreads();
  float ls[4][4];
  #pragma unroll
  for (int mi = 0; mi < 4; ++mi) {
    #pragma unroll
    for (int r = 0; r < 4; ++r) {
      const int row = rowB + mi * 16 + r;
      const float m = fmaxf(lm[mi][r], ovl[(wc ^ 1) * 128 + row]);
      float s = 0.f;
      #pragma unroll
      for (int ni = 0; ni < 4; ++ni) {
        const float v = acc[mi][ni][r];
        const float e = (v > -1e37f) ? expf(v - m) : 0.f;
        acc[mi][ni][r] = e;
        s += e;
      }
      #pragma unroll
      for (int off = 1; off < 16; off <<= 1) s += __shfl_xor(s, off, 64);
      ls[mi][r] = s;
    }
  }
  if (f == 0) {
    #pragma unroll
    for (int mi = 0; mi < 4; ++mi)
      #pragma unroll
      for (int r = 0; r < 4; ++r)
        ovl[256 + wc * 128 + rowB + mi * 16 + r] = ls[mi][r];
  }
  __syncthreads();
  #pragma unroll
  for (int mi = 0; mi < 4; ++mi) {
    #pragma unroll
    for (int r = 0; r < 4; ++r) {
      const int row = rowB + mi * 16 + r;
      const float tot = ls[mi][r] + ovl[256 + (wc ^ 1) * 128 + row];
      const float inv = (tot > 0.f) ? 1.f / tot : 0.f;
      #pragma unroll
      for (int ni = 0; ni < 4; ++ni)
        P[(long long)row * 128 + colB + ni * 16] = f2bf(acc[mi][ni][r] * inv);
    }
  }
}

// ------------------------------------------------------------------
// fused f32 -> bf16 weight conversion
// ------------------------------------------------------------------
struct ConvArgs {
  const float* s[10];
  unsigned short* d[10];
  long long off[11];
};
__global__ __launch_bounds__(256) void convall_kernel(ConvArgs a, long long tot)
{
  const long long i = ((long long)blockIdx.x * 256 + threadIdx.x) * 4;
  if (i >= tot) return;
  int t = 0;
  while (i >= a.off[t + 1]) ++t;
  const long long j = i - a.off[t];
  const float4 v = *(const float4*)(a.s[t] + j);
  const unsigned int lo = (unsigned int)f2bf(v.x) | ((unsigned int)f2bf(v.y) << 16);
  const unsigned int hi = (unsigned int)f2bf(v.z) | ((unsigned int)f2bf(v.w) << 16);
  *(uint2*)(a.d[t] + j) = make_uint2(lo, hi);
}

// ------------------------------------------------------------------
// stage 1: wave-per-token embeddings + LN(256) x2 + pos projection
// ------------------------------------------------------------------
__global__ __launch_bounds__(256) void embed_kernel(
    const int* __restrict__ tids, const int* __restrict__ lids,
    const float* __restrict__ xs, const float* __restrict__ ys, const float* __restrict__ zs,
    const float* __restrict__ temb, const float* __restrict__ lemb,
    const float* __restrict__ tg, const float* __restrict__ tb,
    const float* __restrict__ lg, const float* __restrict__ lb,
    const float* __restrict__ pw, const float* __restrict__ pb,
    unsigned short* __restrict__ hb)
{
  const int tok = blockIdx.x * 4 + (threadIdx.x >> 6);
  const int lane = threadIdx.x & 63;
  const int e0 = lane * 4;
  const int ti = tids[tok], li = lids[tok];
  float4 tv = make_float4(0.f, 0.f, 0.f, 0.f);
  float4 lv = make_float4(0.f, 0.f, 0.f, 0.f);
  if (ti != 0) tv = *(const float4*)(temb + ti * 256 + e0);
  if (li != 0) lv = *(const float4*)(lemb + li * 256 + e0);

  float s0 = tv.x + tv.y + tv.z + tv.w;
  float s1 = tv.x * tv.x + tv.y * tv.y + tv.z * tv.z + tv.w * tv.w;
  float s2 = lv.x + lv.y + lv.z + lv.w;
  float s3 = lv.x * lv.x + lv.y * lv.y + lv.z * lv.z + lv.w * lv.w;
  #pragma unroll
  for (int off = 32; off > 0; off >>= 1) {
    s0 += __shfl_xor(s0, off, 64);
    s1 += __shfl_xor(s1, off, 64);
    s2 += __shfl_xor(s2, off, 64);
    s3 += __shfl_xor(s3, off, 64);
  }
  const float mt = s0 * (1.f / 256.f), vt = s1 * (1.f / 256.f) - mt * mt;
  const float ml = s2 * (1.f / 256.f), vl = s3 * (1.f / 256.f) - ml * ml;
  const float rt = rsqrtf(vt + 1e-5f), rl = rsqrtf(vl + 1e-5f);

  const float4 tg4 = *(const float4*)(tg + e0), tb4 = *(const float4*)(tb + e0);
  const float4 lg4 = *(const float4*)(lg + e0), lb4 = *(const float4*)(lb + e0);
  const size_t base = (size_t)tok * 768;
  ushort4 o;
  o.x = f2bf((tv.x - mt) * rt * tg4.x + tb4.x);
  o.y = f2bf((tv.y - mt) * rt * tg4.y + tb4.y);
  o.z = f2bf((tv.z - mt) * rt * tg4.z + tb4.z);
  o.w = f2bf((tv.w - mt) * rt * tg4.w + tb4.w);
  *(ushort4*)(hb + base + e0) = o;
  o.x = f2bf((lv.x - ml) * rl * lg4.x + lb4.x);
  o.y = f2bf((lv.y - ml) * rl * lg4.y + lb4.y);
  o.z = f2bf((lv.z - ml) * rl * lg4.z + lb4.z);
  o.w = f2bf((lv.w - ml) * rl * lg4.w + lb4.w);
  *(ushort4*)(hb + base + 256 + e0) = o;

  const float X = xs[tok], Y = ys[tok], Z = zs[tok];
  const float4 w0 = *(const float4*)(pw + 12 * lane);
  const float4 w1 = *(const float4*)(pw + 12 * lane + 4);
  const float4 w2 = *(const float4*)(pw + 12 * lane + 8);
  const float4 pb4 = *(const float4*)(pb + e0);
  o.x = f2bf(w0.x * X + w0.y * Y + w0.z * Z + pb4.x);
  o.y = f2bf(w0.w * X + w1.x * Y + w1.y * Z + pb4.y);
  o.z = f2bf(w1.z * X + w1.w * Y + w2.x * Z + pb4.z);
  o.w = f2bf(w2.y * X + w2.z * Y + w2.w * Z + pb4.w);
  *(ushort4*)(hb + base + 512 + e0) = o;
}

// ------------------------------------------------------------------
// LayerNorm, wave-per-row, D=768
// ------------------------------------------------------------------
template<int XBF, int RBF>
__global__ __launch_bounds__(256) void ln_kernel(
    const void* __restrict__ x, const void* __restrict__ res,
    const float* __restrict__ g, const float* __restrict__ b,
    float* __restrict__ yf, unsigned short* __restrict__ yb,
    int nrows, float eps)
{
  const int row = blockIdx.x * 4 + (threadIdx.x >> 6);
  if (row >= nrows) return;
  const int lane = threadIdx.x & 63;
  const size_t base = (size_t)row * 768;
  const int e0 = lane * 12;
  float v[12];
  #pragma unroll
  for (int j = 0; j < 3; ++j) {
    if (XBF) {
      const ushort4 u = *(const ushort4*)((const unsigned short*)x + base + e0 + 4 * j);
      v[4*j+0] = bf2f(u.x); v[4*j+1] = bf2f(u.y); v[4*j+2] = bf2f(u.z); v[4*j+3] = bf2f(u.w);
    } else {
      const float4 fx = *(const float4*)((const float*)x + base + e0 + 4 * j);
      v[4*j+0] = fx.x; v[4*j+1] = fx.y; v[4*j+2] = fx.z; v[4*j+3] = fx.w;
    }
  }
  if (res) {
    #pragma unroll
    for (int j = 0; j < 3; ++j) {
      if (RBF) {
        const ushort4 u = *(const ushort4*)((const unsigned short*)res + base + e0 + 4 * j);
        v[4*j+0] += bf2f(u.x); v[4*j+1] += bf2f(u.y); v[4*j+2] += bf2f(u.z); v[4*j+3] += bf2f(u.w);
      } else {
        const float4 fx = *(const float4*)((const float*)res + base + e0 + 4 * j);
        v[4*j+0] += fx.x; v[4*j+1] += fx.y; v[4*j+2] += fx.z; v[4*j+3] += fx.w;
      }
    }
  }
  float s = 0.f, ss = 0.f;
  #pragma unroll
  for (int j = 0; j < 12; ++j) { s += v[j]; ss += v[j] * v[j]; }
  #pragma unroll
  for (int off = 32; off > 0; off >>= 1) {
    s += __shfl_xor(s, off, 64);
    ss += __shfl_xor(ss, off, 64);
  }
  const float mean = s * (1.f / 768.f);
  const float rstd = rsqrtf(ss * (1.f / 768.f) - mean * mean + eps);
  #pragma unroll
  for (int j = 0; j < 3; ++j) {
    const float4 g4 = *(const float4*)(g + e0 + 4 * j);
    const float4 b4 = *(const float4*)(b + e0 + 4 * j);
    float o0 = (v[4*j+0] - mean) * rstd * g4.x + b4.x;
    float o1 = (v[4*j+1] - mean) * rstd * g4.y + b4.y;
    float o2 = (v[4*j+2] - mean) * rstd * g4.z + b4.z;
    float o3 = (v[4*j+3] - mean) * rstd * g4.w + b4.w;
    if (yf) *(float4*)(yf + base + e0 + 4 * j) = make_float4(o0, o1, o2, o3);
    if (yb) {
      ushort4 u; u.x = f2bf(o0); u.y = f2bf(o1); u.z = f2bf(o2); u.w = f2bf(o3);
      *(ushort4*)(yb + base + e0 + 4 * j) = u;
    }
  }
}

// ------------------------------------------------------------------
// stage-3 masked deberta softmax, wave-per-row -> bf16 [8][128][128]
// ------------------------------------------------------------------
__global__ __launch_bounds__(256) void deb3_kernel(
    const float* __restrict__ sc,   // [8][128][128]
    const float* __restrict__ c2p,  // [640][512]
    const float* __restrict__ p2c,  // [640][512]
    const int* __restrict__ mask,   // [8][80][100]
    unsigned short* __restrict__ probs) // [8][128][128]
{
  const int rid = blockIdx.x * 4 + (threadIdx.x >> 6);
  if (rid >= 640) return;
  const int b = rid / 80, q = rid - b * 80;
  const int lane = threadIdx.x & 63;
  const bool mq = mask[(size_t)rid * 100] > 0;
  float v0 = -3.4e38f, v1 = -3.4e38f;
  bool val0 = false, val1 = false;
  {
    const int k = lane;
    const bool mk = mask[(size_t)(b * 80 + k) * 100] > 0;
    val0 = mq && mk;
    const int r = 256 + q - k;
    if (val0)
      v0 = sc[(size_t)b * 16384 + (size_t)q * 128 + k] +
           (c2p[(size_t)rid * 512 + r] + p2c[(size_t)(b * 80 + k) * 512 + r]) * (1.f / 48.f);
  }
  if (lane + 64 < 80) {
    const int k = lane + 64;
    const bool mk = mask[(size_t)(b * 80 + k) * 100] > 0;
    val1 = mq && mk;
    const int r = 256 + q - k;
    if (val1)
      v1 = sc[(size_t)b * 16384 + (size_t)q * 128 + k] +
           (c2p[(size_t)rid * 512 + r] + p2c[(size_t)(b * 80 + k) * 512 + r]) * (1.f / 48.f);
  }
  float m = fmaxf(v0, v1);
  #pragma unroll
  for (int off = 32; off > 0; off >>= 1) m = fmaxf(m, __shfl_xor(m, off, 64));
  const float e0 = val0 ? expf(v0 - m) : 0.f;
  const float e1 = val1 ? expf(v1 - m) : 0.f;
  float s = e0 + e1;
  #pragma unroll
  for (int off = 32; off > 0; off >>= 1) s += __shfl_xor(s, off, 64);
  const float inv = (s > 0.f) ? 1.f / s : 0.f;
  unsigned short* orow = probs + (size_t)b * 16384 + (size_t)q * 128;
  orow[lane] = val0 ? f2bf(e0 * inv) : (unsigned short)0;
  orow[lane + 64] = val1 ? f2bf(e1 * inv) : (unsigned short)0;
}

// ------------------------------------------------------------------
// means
// ------------------------------------------------------------------
__global__ __launch_bounds__(192) void meanL_kernel(
    const unsigned short* __restrict__ hb, float* __restrict__ hf,
    unsigned short* __restrict__ hfb)
{
  const int bf = blockIdx.x;            // 640
  const int d0 = threadIdx.x * 4;
  float4 acc = make_float4(0.f, 0.f, 0.f, 0.f);
  for (int l = 0; l < 100; ++l) {
    const ushort4 u = *(const ushort4*)(hb + ((size_t)bf * 100 + l) * 768 + d0);
    acc.x += bf2f(u.x); acc.y += bf2f(u.y); acc.z += bf2f(u.z); acc.w += bf2f(u.w);
  }
  acc.x *= 0.01f; acc.y *= 0.01f; acc.z *= 0.01f; acc.w *= 0.01f;
  *(float4*)(hf + (size_t)bf * 768 + d0) = acc;
  ushort4 o; o.x = f2bf(acc.x); o.y = f2bf(acc.y); o.z = f2bf(acc.z); o.w = f2bf(acc.w);
  *(ushort4*)(hfb + (size_t)bf * 768 + d0) = o;
}

__global__ __launch_bounds__(192) void meanF_kernel(const float* __restrict__ h4, float* __restrict__ hm)
{
  const int b = blockIdx.x;             // 8
  const int d0 = threadIdx.x * 4;
  float4 acc = make_float4(0.f, 0.f, 0.f, 0.f);
  for (int f = 0; f < 80; ++f) {
    const float4 u = *(const float4*)(h4 + ((size_t)b * 80 + f) * 768 + d0);
    acc.x += u.x; acc.y += u.y; acc.z += u.z; acc.w += u.w;
  }
  const float k = 1.f / 80.f;
  *(float4*)(hm + (size_t)b * 768 + d0) = make_float4(acc.x * k, acc.y * k, acc.z * k, acc.w * k);
}

// ------------------------------------------------------------------
// head
// ------------------------------------------------------------------
__global__ __launch_bounds__(64) void head_kernel(
    const float* __restrict__ hm, const float* __restrict__ w,
    const float* __restrict__ bias, float* __restrict__ out)
{
  const int n = blockIdx.x, b = blockIdx.y;
  const float* x = hm + (size_t)b * 768;
  const float* wn = w + (size_t)n * 768;
  float s = 0.f;
  for (int i = threadIdx.x * 4; i < 768; i += 256) {
    const float4 xv = *(const float4*)(x + i);
    const float4 wv = *(const float4*)(wn + i);
    s += xv.x * wv.x + xv.y * wv.y + xv.z * wv.z + xv.w * wv.w;
  }
  #pragma unroll
  for (int off = 32; off > 0; off >>= 1) s += __shfl_down(s, off, 64);
  if (threadIdx.x == 0) out[(size_t)b * 250 + n] = s + bias[n];
}

// ------------------------------------------------------------------
// host
// ------------------------------------------------------------------
extern "C" void kernel_launch(void* const* d_in, const int* in_sizes, int n_in,
                              void* d_out, int out_size, void* d_ws, size_t ws_size,
                              hipStream_t stream)
{
  const int*   type_ids   = (const int*)  d_in[0];
  const int*   lm_ids     = (const int*)  d_in[1];
  const float* xs         = (const float*)d_in[2];
  const float* ys         = (const float*)d_in[3];
  const float* zs         = (const float*)d_in[4];
  const int*   mask       = (const int*)  d_in[5];
  const float* type_emb   = (const float*)d_in[6];
  const float* lm_emb     = (const float*)d_in[7];
  const float* type_ln_g  = (const float*)d_in[8];
  const float* type_ln_b  = (const float*)d_in[9];
  const float* lm_ln_g    = (const float*)d_in[10];
  const float* lm_ln_b    = (const float*)d_in[11];
  const float* pos_w      = (const float*)d_in[12];
  const float* pos_b      = (const float*)d_in[13];
  const float* lt_in_w    = (const float*)d_in[14];
  const float* lt_in_b    = (const float*)d_in[15];
  const float* lt_out_w   = (const float*)d_in[16];
  const float* lt_out_b   = (const float*)d_in[17];
  const float* lt_ln1_g   = (const float*)d_in[18];
  const float* lt_ln1_b   = (const float*)d_in[19];
  const float* lt_ff1_w   = (const float*)d_in[20];
  const float* lt_ff1_b   = (const float*)d_in[21];
  const float* lt_ff2_w   = (const float*)d_in[22];
  const float* lt_ff2_b   = (const float*)d_in[23];
  const float* lt_ln2_g   = (const float*)d_in[24];
  const float* lt_ln2_b   = (const float*)d_in[25];
  const float* rel_emb    = (const float*)d_in[26];
  const float* rel_ln_g   = (const float*)d_in[27];
  const float* rel_ln_b   = (const float*)d_in[28];
  const float* dq_w       = (const float*)d_in[29];
  const float* dq_b       = (const float*)d_in[30];
  const float* dk_w       = (const float*)d_in[31];
  const float* dk_b       = (const float*)d_in[32];
  const float* dv_w       = (const float*)d_in[33];
  const float* dv_b       = (const float*)d_in[34];
  const float* dao_w      = (const float*)d_in[35];
  const float* dao_b      = (const float*)d_in[36];
  const float* da_ln_g    = (const float*)d_in[37];
  const float* da_ln_b    = (const float*)d_in[38];
  const float* di_w       = (const float*)d_in[39];
  const float* di_b       = (const float*)d_in[40];
  const float* do_w       = (const float*)d_in[41];
  const float* do_b       = (const float*)d_in[42];
  const float* do_ln_g    = (const float*)d_in[43];
  const float* do_ln_b    = (const float*)d_in[44];
  const float* head_w     = (const float*)d_in[45];
  const float* head_b     = (const float*)d_in[46];
  float* out = (float*)d_out;
  float* ws  = (float*)d_ws;

  const float inv_sqrt_d = 0.03608439182435161f;  // 1/sqrt(768)
  const long long W2 = 768 * 768;

  auto rnd = [](size_t x) { return (x + 63) & ~(size_t)63; };
  const size_t ws_floats = ws_size / sizeof(float);

  // ---- persistent region (float units) ----
  size_t o = 0;
  const size_t offHB = o; o += rnd((size_t)64000 * 768 / 2);   // h bf16
  auto woff = [&](size_t elems) { size_t r = o; o += rnd(elems / 2); return r; };
  const size_t w_in   = woff((size_t)2304 * 768);
  const size_t w_out  = woff((size_t)768 * 768);
  const size_t w_f1   = woff((size_t)768 * 768);
  const size_t w_f2   = woff((size_t)768 * 768);
  const size_t w_qkv3 = woff((size_t)2304 * 768);   // dq|dk|dv
  const size_t w_ao   = woff((size_t)768 * 768);
  const size_t w_di   = woff((size_t)3072 * 768);
  const size_t w_do   = woff((size_t)768 * 3072);
  const size_t b_qkv3 = o; o += rnd(2304);          // f32 concat bias
  const size_t scratch0 = o;

  // ---- stage-3 scratch need ----
  size_t s3need = 0;
  {
    size_t t = 0;
    t += rnd((size_t)640 * 768);          // hf f32
    t += rnd((size_t)1152 * 768 / 2);     // hfbE (hfb + relln rows)
    t += rnd((size_t)1152 * 2304 / 2);    // qp
    t += 2 * (size_t)640 * 512;           // c2p,p2c
    t += rnd((size_t)8 * 16384);          // p32_3
    t += rnd((size_t)8 * 16384 / 2);      // p3bf
    t += rnd((size_t)8 * 98304 / 2);      // vt3
    t += rnd((size_t)640 * 768 / 2);      // ctx3b
    t += 2 * rnd((size_t)640 * 768);      // t3,h3
    t += rnd((size_t)640 * 768 / 2);      // h3b
    t += rnd((size_t)640 * 3072 / 2);     // interb
    t += 2 * rnd((size_t)640 * 768);      // t4,h4
    t += rnd((size_t)8 * 768);            // hm
    s3need = t;
  }

  // ---- pick stage-2 chunk size ----
  auto chunk_need = [&](int c) {
    const size_t R = (size_t)c * 100;
    size_t t = 0;
    t += rnd(R * 2304 / 2);             // qkv
    t += 4 * rnd(R * 768 / 2);          // ctx, t1b, h1b, ffo
    t += rnd((size_t)c * 98304 / 2);    // vt
    t += rnd((size_t)c * 16384 / 2);    // pbf
    return t;
  };
  int C = 1;
  {
    const int cands[] = {640, 320, 160, 80, 40, 20, 10, 5, 2, 1};
    for (int c : cands) {
      const size_t need = scratch0 + (chunk_need(c) > s3need ? chunk_need(c) : s3need);
      if (need <= ws_floats) { C = c; break; }
    }
  }
  const size_t R = (size_t)C * 100;

  // stage-2 chunk layout
  o = scratch0;
  const size_t qkvb = o; o += rnd(R * 2304 / 2);
  const size_t ctxb = o; o += rnd(R * 768 / 2);
  const size_t t1b  = o; o += rnd(R * 768 / 2);
  const size_t h1bb = o; o += rnd(R * 768 / 2);
  const size_t ffob = o; o += rnd(R * 768 / 2);
  const size_t vtb  = o; o += rnd((size_t)C * 98304 / 2);
  const size_t pbf  = o; o += rnd((size_t)C * 16384 / 2);

  auto US = [&](size_t foff) { return (unsigned short*)(ws + foff); };

  // ---------------- fused weight conversion ----------------
  {
    ConvArgs a;
    const float* srcs[10] = {lt_in_w, lt_out_w, lt_ff1_w, lt_ff2_w,
                             dq_w, dk_w, dv_w, dao_w, di_w, do_w};
    unsigned short* dsts[10] = {US(w_in), US(w_out), US(w_f1), US(w_f2),
                                US(w_qkv3), US(w_qkv3) + W2, US(w_qkv3) + 2 * W2,
                                US(w_ao), US(w_di), US(w_do)};
    const long long ns[10] = {2304 * 768, W2, W2, W2, W2, W2, W2, W2,
                              3072 * 768, 3072 * 768};
    long long tot = 0;
    for (int i = 0; i < 10; ++i) { a.s[i] = srcs[i]; a.d[i] = dsts[i]; a.off[i] = tot; tot += ns[i]; }
    a.off[10] = tot;
    convall_kernel<<<(unsigned)((tot / 4 + 255) / 256), 256, 0, stream>>>(a, tot);
  }
  hipMemcpyAsync(ws + b_qkv3,        dq_b, 768 * sizeof(float), hipMemcpyDeviceToDevice, stream);
  hipMemcpyAsync(ws + b_qkv3 + 768,  dk_b, 768 * sizeof(float), hipMemcpyDeviceToDevice, stream);
  hipMemcpyAsync(ws + b_qkv3 + 1536, dv_b, 768 * sizeof(float), hipMemcpyDeviceToDevice, stream);

  // ---------------- stage 1 ----------------
  embed_kernel<<<16000, 256, 0, stream>>>(type_ids, lm_ids, xs, ys, zs,
      type_emb, lm_emb, type_ln_g, type_ln_b, lm_ln_g, lm_ln_b, pos_w, pos_b,
      US(offHB));

  // zero vt pad rows (k in [vrows,128)) -- MANDATORY: stale bytes can be NaN-bf16
  hipMemsetAsync(US(vtb), 0, (size_t)C * 98304 * sizeof(unsigned short), stream);

  // ---------------- stage 2 (chunked over sequences) ----------------
  for (int c0 = 0; c0 < 640; c0 += C) {
    unsigned short* hbc = US(offHB) + (size_t)c0 * 100 * 768;
    const int Rr = C * 100;
    // fused qkv; V (cols>=1536) written transposed into vtb
    mg(stream, 128, 0, true, 0, hbc, US(w_in), lt_in_b, nullptr, 0, US(qkvb),
       US(vtb), 100, Rr,
       Rr, 2304, 768, 768, 768, 2304, 0, 0, 0, 0, 1, 1.f);
    // fused scores + softmax -> bf16 P
    scoresm_kernel<<<dim3(1, 1, C), 256, 0, stream>>>(
        US(qkvb), US(qkvb) + 768, US(pbf), 100, 768, 2304, 230400, 16384, inv_sqrt_d);
    // ctx = P @ V
    mg(stream, 128, 0, true, 0, US(pbf), US(vtb), nullptr, nullptr, 0, US(ctxb),
       nullptr, 0, 0,
       100, 768, 128, 128, 128, 768, 16384, 98304, 76800, 0, C, 1.f);
    // out projection + residual(h) -> t1b
    mg(stream, 128, 0, true, 1, US(ctxb), US(w_out), lt_out_b, hbc, 768, US(t1b),
       nullptr, 0, 0,
       Rr, 768, 768, 768, 768, 768, 0, 0, 0, 0, 1, 1.f);
    ln_kernel<1, 1><<<(Rr + 3) / 4, 256, 0, stream>>>(US(t1b), nullptr,
        lt_ln1_g, lt_ln1_b, nullptr, US(h1bb), Rr, 1e-5f);
    // ff1 (relu)
    mg(stream, 128, 1, true, 0, US(h1bb), US(w_f1), lt_ff1_b, nullptr, 0, US(ffob),
       nullptr, 0, 0,
       Rr, 768, 768, 768, 768, 768, 0, 0, 0, 0, 1, 1.f);
    // ff2 + residual(h1) -> t1b
    mg(stream, 128, 0, true, 1, US(ffob), US(w_f2), lt_ff2_b, US(h1bb), 768, US(t1b),
       nullptr, 0, 0,
       Rr, 768, 768, 768, 768, 768, 0, 0, 0, 0, 1, 1.f);
    ln_kernel<1, 1><<<(Rr + 3) / 4, 256, 0, stream>>>(US(t1b), nullptr,
        lt_ln2_g, lt_ln2_b, nullptr, hbc, Rr, 1e-5f);
  }

  // ---------------- stage 3 layout ----------------
  o = scratch0;
  const size_t hf    = o; o += rnd((size_t)640 * 768);
  const size_t hfbE  = o; o += rnd((size_t)1152 * 768 / 2);
  const size_t qp    = o; o += rnd((size_t)1152 * 2304 / 2);
  const size_t c2p   = o; o += (size_t)640 * 512;
  const size_t p2c   = o; o += (size_t)640 * 512;
  const size_t p32_3 = o; o += rnd((size_t)8 * 16384);
  const size_t p3bf  = o; o += rnd((size_t)8 * 16384 / 2);
  const size_t vt3b  = o; o += rnd((size_t)8 * 98304 / 2);
  const size_t ctx3b = o; o += rnd((size_t)640 * 768 / 2);
  const size_t t3    = o; o += rnd((size_t)640 * 768);
  const size_t h3    = o; o += rnd((size_t)640 * 768);
  const size_t h3b   = o; o += rnd((size_t)640 * 768 / 2);
  const size_t interb= o; o += rnd((size_t)640 * 3072 / 2);
  const size_t t4    = o; o += rnd((size_t)640 * 768);
  const size_t h4    = o; o += rnd((size_t)640 * 768);
  const size_t hm    = o; o += rnd((size_t)8 * 768);

  meanL_kernel<<<640, 192, 0, stream>>>(US(offHB), ws + hf, US(hfbE));
  // rel embedding LN -> rows 640..1151 of hfbE
  ln_kernel<0, 0><<<128, 256, 0, stream>>>(rel_emb, nullptr,
      rel_ln_g, rel_ln_b, nullptr, US(hfbE) + (size_t)640 * 768, 512, 1e-7f);
  // zero vt3 pad
  hipMemsetAsync(US(vt3b), 0, (size_t)8 * 98304 * sizeof(unsigned short), stream);
  // merged q|k|v projection (frames + rel positions); frame-V transposed into vt3
  mg(stream, 64, 0, true, 0, US(hfbE), US(w_qkv3), ws + b_qkv3, nullptr, 0, US(qp),
     US(vt3b), 80, 640,
     1152, 2304, 768, 768, 768, 2304, 0, 0, 0, 0, 1, 1.f);
  // content scores /48, batched over B=8 -> f32
  mg(stream, 64, 0, false, 0, US(qp), US(qp) + 768, nullptr, nullptr, 0, ws + p32_3,
     nullptr, 0, 0,
     80, 80, 768, 2304, 2304, 128, 184320, 184320, 16384, 0, 8, 1.f / 48.f);
  // c2p (q @ posk^T) and p2c (k @ posq^T), batched
  mg(stream, 64, 0, false, 0, US(qp), US(qp) + (size_t)640 * 2304 + 768, nullptr, nullptr, 0, ws + c2p,
     nullptr, 0, 0,
     640, 512, 768, 2304, 2304, 512, 768, -768, 327680, 0, 2, 1.f);
  // masked softmax -> bf16 probs
  deb3_kernel<<<160, 256, 0, stream>>>(ws + p32_3, ws + c2p, ws + p2c, mask, US(p3bf));
  // ctx = P @ V
  mg(stream, 64, 0, true, 0, US(p3bf), US(vt3b), nullptr, nullptr, 0, US(ctx3b),
     nullptr, 0, 0,
     80, 768, 128, 128, 128, 768, 16384, 98304, 61440, 0, 8, 1.f);
  // attention output + residual(hf) -> t3 f32
  mg(stream, 64, 0, false, 2, US(ctx3b), US(w_ao), dao_b, ws + hf, 768, ws + t3,
     nullptr, 0, 0,
     640, 768, 768, 768, 768, 768, 0, 0, 0, 0, 1, 1.f);
  ln_kernel<0, 0><<<160, 256, 0, stream>>>(ws + t3, nullptr,
      da_ln_g, da_ln_b, ws + h3, US(h3b), 640, 1e-7f);
  // FFN (exact gelu)
  mg(stream, 64, 2, true, 0, US(h3b), US(w_di), di_b, nullptr, 0, US(interb),
     nullptr, 0, 0,
     640, 3072, 768, 768, 768, 3072, 0, 0, 0, 0, 1, 1.f);
  // do projection + residual(h3) -> t4 f32
  mg(stream, 64, 0, false, 2, US(interb), US(w_do), do_b, ws + h3, 768, ws + t4,
     nullptr, 0, 0,
     640, 768, 3072, 3072, 3072, 768, 0, 0, 0, 0, 1, 1.f);
  ln_kernel<0, 0><<<160, 256, 0, stream>>>(ws + t4, nullptr,
      do_ln_g, do_ln_b, ws + h4, nullptr, 640, 1e-7f);
  meanF_kernel<<<8, 192, 0, stream>>>(ws + h4, ws + hm);
  head_kernel<<<dim3(250, 8), 64, 0, stream>>>(ws + hm, head_w, head_b, out);
}

// Round 11
// 1954.778 us; speedup vs baseline: 1.0723x; 1.0723x over previous
//
#include <hip/hip_runtime.h>

using short8v = __attribute__((ext_vector_type(8))) short;
using float4v = __attribute__((ext_vector_type(4))) float;

__device__ __forceinline__ unsigned short f2bf(float f) {
  unsigned int u = __float_as_uint(f);
  u += 0x7FFF + ((u >> 16) & 1);
  return (unsigned short)(u >> 16);
}
__device__ __forceinline__ float bf2f(unsigned short u) {
  return __uint_as_float((unsigned int)u << 16);
}

__device__ __forceinline__ int swz(int row, int c) {
  return row * 64 + (c ^ ((row & 7) << 3));
}

// ------------------------------------------------------------------
// bf16 MFMA GEMM, reg-staged + prefetch + LDS XOR swizzle.
// C = act(alpha*A.B^T + bias + resid). BM in {128, 64}. K % 64 == 0.
// RES: 0 none, 1 bf16 resid, 2 f32 resid. Batched via blockIdx.z.
// ------------------------------------------------------------------
template<int BM, int ACT, bool OUTBF, int RES>
__global__ __launch_bounds__(256) void gemm_mfma(
    const unsigned short* __restrict__ A, const unsigned short* __restrict__ B,
    const float* __restrict__ bias, const void* __restrict__ resid, int ldr,
    void* __restrict__ Cv,
    int M, int N, int K, int lda, int ldb, int ldc,
    long long sA, long long sB, long long sC, long long sBias, float alpha)
{
  constexpr int NF = BM / 32;
  A += (long long)blockIdx.z * sA;
  B += (long long)blockIdx.z * sB;
  if (bias) bias += (long long)blockIdx.z * sBias;
  const int m0 = blockIdx.y * BM, n0 = blockIdx.x * BM;

  __shared__ __align__(16) unsigned short As[BM * 64];
  __shared__ __align__(16) unsigned short Bs[BM * 64];

  const int tid = threadIdx.x;
  const int w = tid >> 6, lane = tid & 63;
  const int wr = w >> 1, wc = w & 1;

  const int r0 = tid >> 3;
  const int c8 = (tid & 7) * 8;
  int ra[NF], rb[NF], soff[NF];
  #pragma unroll
  for (int i = 0; i < NF; ++i) {
    int r = m0 + r0 + i * 32; ra[i] = r < M - 1 ? r : M - 1;
    int q = n0 + r0 + i * 32; rb[i] = q < N - 1 ? q : N - 1;
    soff[i] = swz(r0 + i * 32, c8);
  }

  const int fr = lane & 15;
  const int fk = (lane >> 4) * 8;

  float4v acc[NF][NF] = {};

  short8v pa[NF], pb[NF];
  #pragma unroll
  for (int i = 0; i < NF; ++i) {
    pa[i] = *(const short8v*)(A + (long long)ra[i] * lda + c8);
    pb[i] = *(const short8v*)(B + (long long)rb[i] * ldb + c8);
  }

  for (int k0 = 0; k0 < K; k0 += 64) {
    __syncthreads();
    #pragma unroll
    for (int i = 0; i < NF; ++i) {
      *(short8v*)&As[soff[i]] = pa[i];
      *(short8v*)&Bs[soff[i]] = pb[i];
    }
    __syncthreads();
    if (k0 + 64 < K) {
      #pragma unroll
      for (int i = 0; i < NF; ++i) {
        pa[i] = *(const short8v*)(A + (long long)ra[i] * lda + k0 + 64 + c8);
        pb[i] = *(const short8v*)(B + (long long)rb[i] * ldb + k0 + 64 + c8);
      }
    }
    #pragma unroll
    for (int kk = 0; kk < 2; ++kk) {
      short8v a[NF], b[NF];
      #pragma unroll
      for (int i = 0; i < NF; ++i) {
        a[i] = *(const short8v*)&As[swz(wr * (NF * 16) + i * 16 + fr, kk * 32 + fk)];
        b[i] = *(const short8v*)&Bs[swz(wc * (NF * 16) + i * 16 + fr, kk * 32 + fk)];
      }
      #pragma unroll
      for (int mi = 0; mi < NF; ++mi)
        #pragma unroll
        for (int ni = 0; ni < NF; ++ni)
          acc[mi][ni] = __builtin_amdgcn_mfma_f32_16x16x32_bf16(a[mi], b[ni], acc[mi][ni], 0, 0, 0);
    }
  }

  const int ccol0 = n0 + wc * (NF * 16) + (lane & 15);
  const int crow0 = m0 + wr * (NF * 16) + (lane >> 4) * 4;
  float* Cf = (float*)Cv + (long long)blockIdx.z * sC;
  unsigned short* Cb = (unsigned short*)Cv + (long long)blockIdx.z * sC;
  #pragma unroll
  for (int ni = 0; ni < NF; ++ni) {
    const int col = ccol0 + ni * 16;
    if (col >= N) continue;
    const float bs = bias ? bias[col] : 0.f;
    #pragma unroll
    for (int mi = 0; mi < NF; ++mi) {
      #pragma unroll
      for (int r = 0; r < 4; ++r) {
        const int row = crow0 + mi * 16 + r;
        if (row >= M) continue;
        float v = acc[mi][ni][r] * alpha + bs;
        if (RES == 1) v += bf2f(((const unsigned short*)resid)[(long long)row * ldr + col]);
        if (RES == 2) v += ((const float*)resid)[(long long)row * ldr + col];
        if (ACT == 1) v = fmaxf(v, 0.f);
        if (ACT == 2) v = 0.5f * v * (1.f + erff(v * 0.70710678118654752f));
        if (OUTBF) Cb[(long long)row * ldc + col] = f2bf(v);
        else       Cf[(long long)row * ldc + col] = v;
      }
    }
  }
}

static void mg(hipStream_t st, int bm, int act, bool outbf, int res,
               const unsigned short* A, const unsigned short* B,
               const float* bias, const void* resid, int ldr, void* C,
               int M, int N, int K, int lda, int ldb, int ldc,
               long long sA, long long sB, long long sC, long long sBias,
               int bat, float alpha)
{
  dim3 grid((N + bm - 1) / bm, (M + bm - 1) / bm, bat);
  dim3 blk(256);
  #define GEMM_CALL(BM_, A_, O_, R_) \
    gemm_mfma<BM_, A_, O_, R_><<<grid, blk, 0, st>>>(A, B, bias, resid, ldr, C, \
        M, N, K, lda, ldb, ldc, sA, sB, sC, sBias, alpha)
  if (bm == 128) {
    if (outbf) {
      if (act == 1)       GEMM_CALL(128, 1, true, 0);
      else if (res == 1)  GEMM_CALL(128, 0, true, 1);
      else                GEMM_CALL(128, 0, true, 0);
    } else {
      GEMM_CALL(128, 0, false, 0);
    }
  } else {
    if (outbf) {
      if (act == 2)       GEMM_CALL(64, 2, true, 0);
      else                GEMM_CALL(64, 0, true, 0);
    } else {
      if (res == 2)       GEMM_CALL(64, 0, false, 2);
      else                GEMM_CALL(64, 0, false, 0);
    }
  }
  #undef GEMM_CALL
}

// ------------------------------------------------------------------
// fused score + softmax: P = softmax(Q.K^T * alpha) -> bf16 [128][128]
// One block per sequence (full rows in-register). Valid cols < Mv.
// ------------------------------------------------------------------
__global__ __launch_bounds__(256) void scoresm_kernel(
    const unsigned short* __restrict__ Q, const unsigned short* __restrict__ Kp,
    unsigned short* __restrict__ P,
    int Mv, int K, int lda, long long sQ, long long sP, float alpha)
{
  const int z = blockIdx.z;
  Q  += (long long)z * sQ;
  Kp += (long long)z * sQ;
  P  += (long long)z * sP;

  __shared__ __align__(16) unsigned short As[128 * 64];
  __shared__ __align__(16) unsigned short Bs[128 * 64];
  float* ovl = (float*)As;          // overlay after phase 1: [0..255] max, [256..511] sum

  const int tid = threadIdx.x;
  const int w = tid >> 6, lane = tid & 63;
  const int wr = w >> 1, wc = w & 1;
  const int r0 = tid >> 3, c8 = (tid & 7) * 8;

  int ra[4], soff[4];
  #pragma unroll
  for (int i = 0; i < 4; ++i) {
    int r = r0 + i * 32;
    ra[i] = (r < Mv - 1 ? r : Mv - 1);
    soff[i] = swz(r, c8);
  }
  const int fr = lane & 15, fk = (lane >> 4) * 8;

  float4v acc[4][4] = {};
  short8v pa[4], pb[4];
  #pragma unroll
  for (int i = 0; i < 4; ++i) {
    pa[i] = *(const short8v*)(Q  + (long long)ra[i] * lda + c8);
    pb[i] = *(const short8v*)(Kp + (long long)ra[i] * lda + c8);
  }
  for (int k0 = 0; k0 < K; k0 += 64) {
    __syncthreads();
    #pragma unroll
    for (int i = 0; i < 4; ++i) {
      *(short8v*)&As[soff[i]] = pa[i];
      *(short8v*)&Bs[soff[i]] = pb[i];
    }
    __syncthreads();
    if (k0 + 64 < K) {
      #pragma unroll
      for (int i = 0; i < 4; ++i) {
        pa[i] = *(const short8v*)(Q  + (long long)ra[i] * lda + k0 + 64 + c8);
        pb[i] = *(const short8v*)(Kp + (long long)ra[i] * lda + k0 + 64 + c8);
      }
    }
    #pragma unroll
    for (int kk = 0; kk < 2; ++kk) {
      short8v a[4], b[4];
      #pragma unroll
      for (int i = 0; i < 4; ++i) {
        a[i] = *(const short8v*)&As[swz(wr * 64 + i * 16 + fr, kk * 32 + fk)];
        b[i] = *(const short8v*)&Bs[swz(wc * 64 + i * 16 + fr, kk * 32 + fk)];
      }
      #pragma unroll
      for (int mi = 0; mi < 4; ++mi)
        #pragma unroll
        for (int ni = 0; ni < 4; ++ni)
          acc[mi][ni] = __builtin_amdgcn_mfma_f32_16x16x32_bf16(a[mi], b[ni], acc[mi][ni], 0, 0, 0);
    }
  }
  __syncthreads();                  // As reads done -> overlay safe

  const int g = lane >> 4, f = lane & 15;
  const int colB = wc * 64 + f;
  const int rowB = wr * 64 + g * 4;

  bool cv[4];
  #pragma unroll
  for (int ni = 0; ni < 4; ++ni) cv[ni] = (colB + ni * 16) < Mv;

  float lm[4][4];
  #pragma unroll
  for (int mi = 0; mi < 4; ++mi) {
    #pragma unroll
    for (int r = 0; r < 4; ++r) {
      float mx = -3.4e38f;
      #pragma unroll
      for (int ni = 0; ni < 4; ++ni) {
        float v = cv[ni] ? acc[mi][ni][r] * alpha : -3.4e38f;
        acc[mi][ni][r] = v;
        mx = fmaxf(mx, v);
      }
      #pragma unroll
      for (int off = 1; off < 16; off <<= 1) mx = fmaxf(mx, __shfl_xor(mx, off, 64));
      lm[mi][r] = mx;
    }
  }
  if (f == 0) {
    #pragma unroll
    for (int mi = 0; mi < 4; ++mi)
      #pragma unroll
      for (int r = 0; r < 4; ++r)
        ovl[wc * 128 + rowB + mi * 16 + r] = lm[mi][r];
  }
  __syncthreads();
  float ls[4][4];
  #pragma unroll
  for (int mi = 0; mi < 4; ++mi) {
    #pragma unroll
    for (int r = 0; r < 4; ++r) {
      const int row = rowB + mi * 16 + r;
      const float m = fmaxf(lm[mi][r], ovl[(wc ^ 1) * 128 + row]);
      float s = 0.f;
      #pragma unroll
      for (int ni = 0; ni < 4; ++ni) {
        const float v = acc[mi][ni][r];
        const float e = (v > -1e37f) ? expf(v - m) : 0.f;
        acc[mi][ni][r] = e;
        s += e;
      }
      #pragma unroll
      for (int off = 1; off < 16; off <<= 1) s += __shfl_xor(s, off, 64);
      ls[mi][r] = s;
    }
  }
  if (f == 0) {
    #pragma unroll
    for (int mi = 0; mi < 4; ++mi)
      #pragma unroll
      for (int r = 0; r < 4; ++r)
        ovl[256 + wc * 128 + rowB + mi * 16 + r] = ls[mi][r];
  }
  __syncthreads();
  #pragma unroll
  for (int mi = 0; mi < 4; ++mi) {
    #pragma unroll
    for (int r = 0; r < 4; ++r) {
      const int row = rowB + mi * 16 + r;
      const float tot = ls[mi][r] + ovl[256 + (wc ^ 1) * 128 + row];
      const float inv = (tot > 0.f) ? 1.f / tot : 0.f;
      #pragma unroll
      for (int ni = 0; ni < 4; ++ni)
        P[(long long)row * 128 + colB + ni * 16] = f2bf(acc[mi][ni][r] * inv);
    }
  }
}

// ------------------------------------------------------------------
// fused f32 -> bf16 weight conversion
// ------------------------------------------------------------------
struct ConvArgs {
  const float* s[10];
  unsigned short* d[10];
  long long off[11];
};
__global__ __launch_bounds__(256) void convall_kernel(ConvArgs a, long long tot)
{
  const long long i = ((long long)blockIdx.x * 256 + threadIdx.x) * 4;
  if (i >= tot) return;
  int t = 0;
  while (i >= a.off[t + 1]) ++t;
  const long long j = i - a.off[t];
  const float4 v = *(const float4*)(a.s[t] + j);
  const unsigned int lo = (unsigned int)f2bf(v.x) | ((unsigned int)f2bf(v.y) << 16);
  const unsigned int hi = (unsigned int)f2bf(v.z) | ((unsigned int)f2bf(v.w) << 16);
  *(uint2*)(a.d[t] + j) = make_uint2(lo, hi);
}

// ------------------------------------------------------------------
// stage 1: wave-per-token embeddings + LN(256) x2 + pos projection
// ------------------------------------------------------------------
__global__ __launch_bounds__(256) void embed_kernel(
    const int* __restrict__ tids, const int* __restrict__ lids,
    const float* __restrict__ xs, const float* __restrict__ ys, const float* __restrict__ zs,
    const float* __restrict__ temb, const float* __restrict__ lemb,
    const float* __restrict__ tg, const float* __restrict__ tb,
    const float* __restrict__ lg, const float* __restrict__ lb,
    const float* __restrict__ pw, const float* __restrict__ pb,
    unsigned short* __restrict__ hb)
{
  const int tok = blockIdx.x * 4 + (threadIdx.x >> 6);
  const int lane = threadIdx.x & 63;
  const int e0 = lane * 4;
  const int ti = tids[tok], li = lids[tok];
  float4 tv = make_float4(0.f, 0.f, 0.f, 0.f);
  float4 lv = make_float4(0.f, 0.f, 0.f, 0.f);
  if (ti != 0) tv = *(const float4*)(temb + ti * 256 + e0);
  if (li != 0) lv = *(const float4*)(lemb + li * 256 + e0);

  float s0 = tv.x + tv.y + tv.z + tv.w;
  float s1 = tv.x * tv.x + tv.y * tv.y + tv.z * tv.z + tv.w * tv.w;
  float s2 = lv.x + lv.y + lv.z + lv.w;
  float s3 = lv.x * lv.x + lv.y * lv.y + lv.z * lv.z + lv.w * lv.w;
  #pragma unroll
  for (int off = 32; off > 0; off >>= 1) {
    s0 += __shfl_xor(s0, off, 64);
    s1 += __shfl_xor(s1, off, 64);
    s2 += __shfl_xor(s2, off, 64);
    s3 += __shfl_xor(s3, off, 64);
  }
  const float mt = s0 * (1.f / 256.f), vt = s1 * (1.f / 256.f) - mt * mt;
  const float ml = s2 * (1.f / 256.f), vl = s3 * (1.f / 256.f) - ml * ml;
  const float rt = rsqrtf(vt + 1e-5f), rl = rsqrtf(vl + 1e-5f);

  const float4 tg4 = *(const float4*)(tg + e0), tb4 = *(const float4*)(tb + e0);
  const float4 lg4 = *(const float4*)(lg + e0), lb4 = *(const float4*)(lb + e0);
  const size_t base = (size_t)tok * 768;
  ushort4 o;
  o.x = f2bf((tv.x - mt) * rt * tg4.x + tb4.x);
  o.y = f2bf((tv.y - mt) * rt * tg4.y + tb4.y);
  o.z = f2bf((tv.z - mt) * rt * tg4.z + tb4.z);
  o.w = f2bf((tv.w - mt) * rt * tg4.w + tb4.w);
  *(ushort4*)(hb + base + e0) = o;
  o.x = f2bf((lv.x - ml) * rl * lg4.x + lb4.x);
  o.y = f2bf((lv.y - ml) * rl * lg4.y + lb4.y);
  o.z = f2bf((lv.z - ml) * rl * lg4.z + lb4.z);
  o.w = f2bf((lv.w - ml) * rl * lg4.w + lb4.w);
  *(ushort4*)(hb + base + 256 + e0) = o;

  const float X = xs[tok], Y = ys[tok], Z = zs[tok];
  const float4 w0 = *(const float4*)(pw + 12 * lane);
  const float4 w1 = *(const float4*)(pw + 12 * lane + 4);
  const float4 w2 = *(const float4*)(pw + 12 * lane + 8);
  const float4 pb4 = *(const float4*)(pb + e0);
  o.x = f2bf(w0.x * X + w0.y * Y + w0.z * Z + pb4.x);
  o.y = f2bf(w0.w * X + w1.x * Y + w1.y * Z + pb4.y);
  o.z = f2bf(w1.z * X + w1.w * Y + w2.x * Z + pb4.z);
  o.w = f2bf(w2.y * X + w2.z * Y + w2.w * Z + pb4.w);
  *(ushort4*)(hb + base + 512 + e0) = o;
}

// ------------------------------------------------------------------
// LayerNorm, wave-per-row, D=768
// ------------------------------------------------------------------
template<int XBF, int RBF>
__global__ __launch_bounds__(256) void ln_kernel(
    const void* __restrict__ x, const void* __restrict__ res,
    const float* __restrict__ g, const float* __restrict__ b,
    float* __restrict__ yf, unsigned short* __restrict__ yb,
    int nrows, float eps)
{
  const int row = blockIdx.x * 4 + (threadIdx.x >> 6);
  if (row >= nrows) return;
  const int lane = threadIdx.x & 63;
  const size_t base = (size_t)row * 768;
  const int e0 = lane * 12;
  float v[12];
  #pragma unroll
  for (int j = 0; j < 3; ++j) {
    if (XBF) {
      const ushort4 u = *(const ushort4*)((const unsigned short*)x + base + e0 + 4 * j);
      v[4*j+0] = bf2f(u.x); v[4*j+1] = bf2f(u.y); v[4*j+2] = bf2f(u.z); v[4*j+3] = bf2f(u.w);
    } else {
      const float4 fx = *(const float4*)((const float*)x + base + e0 + 4 * j);
      v[4*j+0] = fx.x; v[4*j+1] = fx.y; v[4*j+2] = fx.z; v[4*j+3] = fx.w;
    }
  }
  if (res) {
    #pragma unroll
    for (int j = 0; j < 3; ++j) {
      if (RBF) {
        const ushort4 u = *(const ushort4*)((const unsigned short*)res + base + e0 + 4 * j);
        v[4*j+0] += bf2f(u.x); v[4*j+1] += bf2f(u.y); v[4*j+2] += bf2f(u.z); v[4*j+3] += bf2f(u.w);
      } else {
        const float4 fx = *(const float4*)((const float*)res + base + e0 + 4 * j);
        v[4*j+0] += fx.x; v[4*j+1] += fx.y; v[4*j+2] += fx.z; v[4*j+3] += fx.w;
      }
    }
  }
  float s = 0.f, ss = 0.f;
  #pragma unroll
  for (int j = 0; j < 12; ++j) { s += v[j]; ss += v[j] * v[j]; }
  #pragma unroll
  for (int off = 32; off > 0; off >>= 1) {
    s += __shfl_xor(s, off, 64);
    ss += __shfl_xor(ss, off, 64);
  }
  const float mean = s * (1.f / 768.f);
  const float rstd = rsqrtf(ss * (1.f / 768.f) - mean * mean + eps);
  #pragma unroll
  for (int j = 0; j < 3; ++j) {
    const float4 g4 = *(const float4*)(g + e0 + 4 * j);
    const float4 b4 = *(const float4*)(b + e0 + 4 * j);
    float o0 = (v[4*j+0] - mean) * rstd * g4.x + b4.x;
    float o1 = (v[4*j+1] - mean) * rstd * g4.y + b4.y;
    float o2 = (v[4*j+2] - mean) * rstd * g4.z + b4.z;
    float o3 = (v[4*j+3] - mean) * rstd * g4.w + b4.w;
    if (yf) *(float4*)(yf + base + e0 + 4 * j) = make_float4(o0, o1, o2, o3);
    if (yb) {
      ushort4 u; u.x = f2bf(o0); u.y = f2bf(o1); u.z = f2bf(o2); u.w = f2bf(o3);
      *(ushort4*)(yb + base + e0 + 4 * j) = u;
    }
  }
}

// ------------------------------------------------------------------
// V transpose: v[b][k][rs-strided] (k<Lk) -> vt[b][d][128] zero-padded
// ------------------------------------------------------------------
__global__ __launch_bounds__(256) void vtrans_kernel(
    const unsigned short* __restrict__ v, unsigned short* __restrict__ vt,
    int Lk, int rs, long long sIn, long long sOut)
{
  __shared__ unsigned short s[64][132];
  const int b = blockIdx.y, d0 = blockIdx.x * 64;
  const unsigned short* vb = v + (long long)b * sIn;
  unsigned short* ob = vt + (long long)b * sOut;
  for (int idx = threadIdx.x; idx < 128 * 64; idx += 256) {
    const int k = idx >> 6, dd = idx & 63;
    s[dd][k] = (k < Lk) ? vb[(long long)k * rs + d0 + dd] : (unsigned short)0;
  }
  __syncthreads();
  for (int idx = threadIdx.x; idx < 64 * 128; idx += 256) {
    const int dd = idx >> 7, k = idx & 127;
    ob[(long long)(d0 + dd) * 128 + k] = s[dd][k];
  }
}

// ------------------------------------------------------------------
// stage-3 masked deberta softmax, wave-per-row -> bf16 [8][128][128]
// ------------------------------------------------------------------
__global__ __launch_bounds__(256) void deb3_kernel(
    const float* __restrict__ sc,   // [8][128][128]
    const float* __restrict__ c2p,  // [640][512]
    const float* __restrict__ p2c,  // [640][512]
    const int* __restrict__ mask,   // [8][80][100]
    unsigned short* __restrict__ probs) // [8][128][128]
{
  const int rid = blockIdx.x * 4 + (threadIdx.x >> 6);
  if (rid >= 640) return;
  const int b = rid / 80, q = rid - b * 80;
  const int lane = threadIdx.x & 63;
  const bool mq = mask[(size_t)rid * 100] > 0;
  float v0 = -3.4e38f, v1 = -3.4e38f;
  bool val0 = false, val1 = false;
  {
    const int k = lane;
    const bool mk = mask[(size_t)(b * 80 + k) * 100] > 0;
    val0 = mq && mk;
    const int r = 256 + q - k;
    if (val0)
      v0 = sc[(size_t)b * 16384 + (size_t)q * 128 + k] +
           (c2p[(size_t)rid * 512 + r] + p2c[(size_t)(b * 80 + k) * 512 + r]) * (1.f / 48.f);
  }
  if (lane + 64 < 80) {
    const int k = lane + 64;
    const bool mk = mask[(size_t)(b * 80 + k) * 100] > 0;
    val1 = mq && mk;
    const int r = 256 + q - k;
    if (val1)
      v1 = sc[(size_t)b * 16384 + (size_t)q * 128 + k] +
           (c2p[(size_t)rid * 512 + r] + p2c[(size_t)(b * 80 + k) * 512 + r]) * (1.f / 48.f);
  }
  float m = fmaxf(v0, v1);
  #pragma unroll
  for (int off = 32; off > 0; off >>= 1) m = fmaxf(m, __shfl_xor(m, off, 64));
  const float e0 = val0 ? expf(v0 - m) : 0.f;
  const float e1 = val1 ? expf(v1 - m) : 0.f;
  float s = e0 + e1;
  #pragma unroll
  for (int off = 32; off > 0; off >>= 1) s += __shfl_xor(s, off, 64);
  const float inv = (s > 0.f) ? 1.f / s : 0.f;
  unsigned short* orow = probs + (size_t)b * 16384 + (size_t)q * 128;
  orow[lane] = val0 ? f2bf(e0 * inv) : (unsigned short)0;
  orow[lane + 64] = val1 ? f2bf(e1 * inv) : (unsigned short)0;
}

// ------------------------------------------------------------------
// means
// ------------------------------------------------------------------
__global__ __launch_bounds__(192) void meanL_kernel(
    const unsigned short* __restrict__ hb, float* __restrict__ hf,
    unsigned short* __restrict__ hfb)
{
  const int bf = blockIdx.x;            // 640
  const int d0 = threadIdx.x * 4;
  float4 acc = make_float4(0.f, 0.f, 0.f, 0.f);
  for (int l = 0; l < 100; ++l) {
    const ushort4 u = *(const ushort4*)(hb + ((size_t)bf * 100 + l) * 768 + d0);
    acc.x += bf2f(u.x); acc.y += bf2f(u.y); acc.z += bf2f(u.z); acc.w += bf2f(u.w);
  }
  acc.x *= 0.01f; acc.y *= 0.01f; acc.z *= 0.01f; acc.w *= 0.01f;
  *(float4*)(hf + (size_t)bf * 768 + d0) = acc;
  ushort4 o; o.x = f2bf(acc.x); o.y = f2bf(acc.y); o.z = f2bf(acc.z); o.w = f2bf(acc.w);
  *(ushort4*)(hfb + (size_t)bf * 768 + d0) = o;
}

__global__ __launch_bounds__(192) void meanF_kernel(const float* __restrict__ h4, float* __restrict__ hm)
{
  const int b = blockIdx.x;             // 8
  const int d0 = threadIdx.x * 4;
  float4 acc = make_float4(0.f, 0.f, 0.f, 0.f);
  for (int f = 0; f < 80; ++f) {
    const float4 u = *(const float4*)(h4 + ((size_t)b * 80 + f) * 768 + d0);
    acc.x += u.x; acc.y += u.y; acc.z += u.z; acc.w += u.w;
  }
  const float k = 1.f / 80.f;
  *(float4*)(hm + (size_t)b * 768 + d0) = make_float4(acc.x * k, acc.y * k, acc.z * k, acc.w * k);
}

// ------------------------------------------------------------------
// head
// ------------------------------------------------------------------
__global__ __launch_bounds__(64) void head_kernel(
    const float* __restrict__ hm, const float* __restrict__ w,
    const float* __restrict__ bias, float* __restrict__ out)
{
  const int n = blockIdx.x, b = blockIdx.y;
  const float* x = hm + (size_t)b * 768;
  const float* wn = w + (size_t)n * 768;
  float s = 0.f;
  for (int i = threadIdx.x * 4; i < 768; i += 256) {
    const float4 xv = *(const float4*)(x + i);
    const float4 wv = *(const float4*)(wn + i);
    s += xv.x * wv.x + xv.y * wv.y + xv.z * wv.z + xv.w * wv.w;
  }
  #pragma unroll
  for (int off = 32; off > 0; off >>= 1) s += __shfl_down(s, off, 64);
  if (threadIdx.x == 0) out[(size_t)b * 250 + n] = s + bias[n];
}

// ------------------------------------------------------------------
// host
// ------------------------------------------------------------------
extern "C" void kernel_launch(void* const* d_in, const int* in_sizes, int n_in,
                              void* d_out, int out_size, void* d_ws, size_t ws_size,
                              hipStream_t stream)
{
  const int*   type_ids   = (const int*)  d_in[0];
  const int*   lm_ids     = (const int*)  d_in[1];
  const float* xs         = (const float*)d_in[2];
  const float* ys         = (const float*)d_in[3];
  const float* zs         = (const float*)d_in[4];
  const int*   mask       = (const int*)  d_in[5];
  const float* type_emb   = (const float*)d_in[6];
  const float* lm_emb     = (const float*)d_in[7];
  const float* type_ln_g  = (const float*)d_in[8];
  const float* type_ln_b  = (const float*)d_in[9];
  const float* lm_ln_g    = (const float*)d_in[10];
  const float* lm_ln_b    = (const float*)d_in[11];
  const float* pos_w      = (const float*)d_in[12];
  const float* pos_b      = (const float*)d_in[13];
  const float* lt_in_w    = (const float*)d_in[14];
  const float* lt_in_b    = (const float*)d_in[15];
  const float* lt_out_w   = (const float*)d_in[16];
  const float* lt_out_b   = (const float*)d_in[17];
  const float* lt_ln1_g   = (const float*)d_in[18];
  const float* lt_ln1_b   = (const float*)d_in[19];
  const float* lt_ff1_w   = (const float*)d_in[20];
  const float* lt_ff1_b   = (const float*)d_in[21];
  const float* lt_ff2_w   = (const float*)d_in[22];
  const float* lt_ff2_b   = (const float*)d_in[23];
  const float* lt_ln2_g   = (const float*)d_in[24];
  const float* lt_ln2_b   = (const float*)d_in[25];
  const float* rel_emb    = (const float*)d_in[26];
  const float* rel_ln_g   = (const float*)d_in[27];
  const float* rel_ln_b   = (const float*)d_in[28];
  const float* dq_w       = (const float*)d_in[29];
  const float* dq_b       = (const float*)d_in[30];
  const float* dk_w       = (const float*)d_in[31];
  const float* dk_b       = (const float*)d_in[32];
  const float* dv_w       = (const float*)d_in[33];
  const float* dv_b       = (const float*)d_in[34];
  const float* dao_w      = (const float*)d_in[35];
  const float* dao_b      = (const float*)d_in[36];
  const float* da_ln_g    = (const float*)d_in[37];
  const float* da_ln_b    = (const float*)d_in[38];
  const float* di_w       = (const float*)d_in[39];
  const float* di_b       = (const float*)d_in[40];
  const float* do_w       = (const float*)d_in[41];
  const float* do_b       = (const float*)d_in[42];
  const float* do_ln_g    = (const float*)d_in[43];
  const float* do_ln_b    = (const float*)d_in[44];
  const float* head_w     = (const float*)d_in[45];
  const float* head_b     = (const float*)d_in[46];
  float* out = (float*)d_out;
  float* ws  = (float*)d_ws;

  const float inv_sqrt_d = 0.03608439182435161f;  // 1/sqrt(768)
  const long long W2 = 768 * 768;

  auto rnd = [](size_t x) { return (x + 63) & ~(size_t)63; };
  const size_t ws_floats = ws_size / sizeof(float);

  // ---- persistent region (float units) ----
  size_t o = 0;
  const size_t offHB = o; o += rnd((size_t)64000 * 768 / 2);   // h bf16
  auto woff = [&](size_t elems) { size_t r = o; o += rnd(elems / 2); return r; };
  const size_t w_in   = woff((size_t)2304 * 768);
  const size_t w_out  = woff((size_t)768 * 768);
  const size_t w_f1   = woff((size_t)768 * 768);
  const size_t w_f2   = woff((size_t)768 * 768);
  const size_t w_qkv3 = woff((size_t)2304 * 768);   // dq|dk|dv
  const size_t w_ao   = woff((size_t)768 * 768);
  const size_t w_di   = woff((size_t)3072 * 768);
  const size_t w_do   = woff((size_t)768 * 3072);
  const size_t b_qkv3 = o; o += rnd(2304);          // f32 concat bias
  const size_t scratch0 = o;

  // ---- stage-3 scratch need ----
  size_t s3need = 0;
  {
    size_t t = 0;
    t += rnd((size_t)640 * 768);          // hf f32
    t += rnd((size_t)1152 * 768 / 2);     // hfbE (hfb + relln rows)
    t += rnd((size_t)1152 * 2304 / 2);    // qp
    t += 2 * (size_t)640 * 512;           // c2p,p2c
    t += rnd((size_t)8 * 16384);          // p32_3
    t += rnd((size_t)8 * 16384 / 2);      // p3bf
    t += rnd((size_t)8 * 98304 / 2);      // vt3
    t += rnd((size_t)640 * 768 / 2);      // ctx3b
    t += 2 * rnd((size_t)640 * 768);      // t3,h3
    t += rnd((size_t)640 * 768 / 2);      // h3b
    t += rnd((size_t)640 * 3072 / 2);     // interb
    t += 2 * rnd((size_t)640 * 768);      // t4,h4
    t += rnd((size_t)8 * 768);            // hm
    s3need = t;
  }

  // ---- pick stage-2 chunk size ----
  auto chunk_need = [&](int c) {
    const size_t R = (size_t)c * 100;
    size_t t = 0;
    t += rnd(R * 2304 / 2);             // qkv
    t += 4 * rnd(R * 768 / 2);          // ctx, t1b, h1b, ffo
    t += rnd((size_t)c * 98304 / 2);    // vt
    t += rnd((size_t)c * 16384 / 2);    // pbf
    return t;
  };
  int C = 1;
  {
    const int cands[] = {640, 320, 160, 80, 40, 20, 10, 5, 2, 1};
    for (int c : cands) {
      const size_t need = scratch0 + (chunk_need(c) > s3need ? chunk_need(c) : s3need);
      if (need <= ws_floats) { C = c; break; }
    }
  }
  const size_t R = (size_t)C * 100;

  // stage-2 chunk layout
  o = scratch0;
  const size_t qkvb = o; o += rnd(R * 2304 / 2);
  const size_t ctxb = o; o += rnd(R * 768 / 2);
  const size_t t1b  = o; o += rnd(R * 768 / 2);
  const size_t h1bb = o; o += rnd(R * 768 / 2);
  const size_t ffob = o; o += rnd(R * 768 / 2);
  const size_t vtb  = o; o += rnd((size_t)C * 98304 / 2);
  const size_t pbf  = o; o += rnd((size_t)C * 16384 / 2);

  auto US = [&](size_t foff) { return (unsigned short*)(ws + foff); };

  // ---------------- fused weight conversion ----------------
  {
    ConvArgs a;
    const float* srcs[10] = {lt_in_w, lt_out_w, lt_ff1_w, lt_ff2_w,
                             dq_w, dk_w, dv_w, dao_w, di_w, do_w};
    unsigned short* dsts[10] = {US(w_in), US(w_out), US(w_f1), US(w_f2),
                                US(w_qkv3), US(w_qkv3) + W2, US(w_qkv3) + 2 * W2,
                                US(w_ao), US(w_di), US(w_do)};
    const long long ns[10] = {2304 * 768, W2, W2, W2, W2, W2, W2, W2,
                              3072 * 768, 3072 * 768};
    long long tot = 0;
    for (int i = 0; i < 10; ++i) { a.s[i] = srcs[i]; a.d[i] = dsts[i]; a.off[i] = tot; tot += ns[i]; }
    a.off[10] = tot;
    convall_kernel<<<(unsigned)((tot / 4 + 255) / 256), 256, 0, stream>>>(a, tot);
  }
  hipMemcpyAsync(ws + b_qkv3,        dq_b, 768 * sizeof(float), hipMemcpyDeviceToDevice, stream);
  hipMemcpyAsync(ws + b_qkv3 + 768,  dk_b, 768 * sizeof(float), hipMemcpyDeviceToDevice, stream);
  hipMemcpyAsync(ws + b_qkv3 + 1536, dv_b, 768 * sizeof(float), hipMemcpyDeviceToDevice, stream);

  // ---------------- stage 1 ----------------
  embed_kernel<<<16000, 256, 0, stream>>>(type_ids, lm_ids, xs, ys, zs,
      type_emb, lm_emb, type_ln_g, type_ln_b, lm_ln_g, lm_ln_b, pos_w, pos_b,
      US(offHB));

  // ---------------- stage 2 (chunked over sequences) ----------------
  for (int c0 = 0; c0 < 640; c0 += C) {
    unsigned short* hbc = US(offHB) + (size_t)c0 * 100 * 768;
    const int Rr = C * 100;
    // fused qkv
    mg(stream, 128, 0, true, 0, hbc, US(w_in), lt_in_b, nullptr, 0, US(qkvb),
       Rr, 2304, 768, 768, 768, 2304, 0, 0, 0, 0, 1, 1.f);
    // fused scores + softmax -> bf16 P
    scoresm_kernel<<<dim3(1, 1, C), 256, 0, stream>>>(
        US(qkvb), US(qkvb) + 768, US(pbf), 100, 768, 2304, 230400, 16384, inv_sqrt_d);
    // V transpose + ctx = P @ V
    vtrans_kernel<<<dim3(12, C), 256, 0, stream>>>(US(qkvb) + 1536, US(vtb), 100, 2304, 230400, 98304);
    mg(stream, 128, 0, true, 0, US(pbf), US(vtb), nullptr, nullptr, 0, US(ctxb),
       100, 768, 128, 128, 128, 768, 16384, 98304, 76800, 0, C, 1.f);
    // out projection + residual(h) -> t1b
    mg(stream, 128, 0, true, 1, US(ctxb), US(w_out), lt_out_b, hbc, 768, US(t1b),
       Rr, 768, 768, 768, 768, 768, 0, 0, 0, 0, 1, 1.f);
    ln_kernel<1, 1><<<(Rr + 3) / 4, 256, 0, stream>>>(US(t1b), nullptr,
        lt_ln1_g, lt_ln1_b, nullptr, US(h1bb), Rr, 1e-5f);
    // ff1 (relu)
    mg(stream, 128, 1, true, 0, US(h1bb), US(w_f1), lt_ff1_b, nullptr, 0, US(ffob),
       Rr, 768, 768, 768, 768, 768, 0, 0, 0, 0, 1, 1.f);
    // ff2 + residual(h1) -> t1b
    mg(stream, 128, 0, true, 1, US(ffob), US(w_f2), lt_ff2_b, US(h1bb), 768, US(t1b),
       Rr, 768, 768, 768, 768, 768, 0, 0, 0, 0, 1, 1.f);
    ln_kernel<1, 1><<<(Rr + 3) / 4, 256, 0, stream>>>(US(t1b), nullptr,
        lt_ln2_g, lt_ln2_b, nullptr, hbc, Rr, 1e-5f);
  }

  // ---------------- stage 3 layout ----------------
  o = scratch0;
  const size_t hf    = o; o += rnd((size_t)640 * 768);
  const size_t hfbE  = o; o += rnd((size_t)1152 * 768 / 2);
  const size_t qp    = o; o += rnd((size_t)1152 * 2304 / 2);
  const size_t c2p   = o; o += (size_t)640 * 512;
  const size_t p2c   = o; o += (size_t)640 * 512;
  const size_t p32_3 = o; o += rnd((size_t)8 * 16384);
  const size_t p3bf  = o; o += rnd((size_t)8 * 16384 / 2);
  const size_t vt3b  = o; o += rnd((size_t)8 * 98304 / 2);
  const size_t ctx3b = o; o += rnd((size_t)640 * 768 / 2);
  const size_t t3    = o; o += rnd((size_t)640 * 768);
  const size_t h3    = o; o += rnd((size_t)640 * 768);
  const size_t h3b   = o; o += rnd((size_t)640 * 768 / 2);
  const size_t interb= o; o += rnd((size_t)640 * 3072 / 2);
  const size_t t4    = o; o += rnd((size_t)640 * 768);
  const size_t h4    = o; o += rnd((size_t)640 * 768);
  const size_t hm    = o; o += rnd((size_t)8 * 768);

  meanL_kernel<<<640, 192, 0, stream>>>(US(offHB), ws + hf, US(hfbE));
  // rel embedding LN -> rows 640..1151 of hfbE
  ln_kernel<0, 0><<<128, 256, 0, stream>>>(rel_emb, nullptr,
      rel_ln_g, rel_ln_b, nullptr, US(hfbE) + (size_t)640 * 768, 512, 1e-7f);
  // merged q|k|v projection for frames AND rel positions
  mg(stream, 64, 0, true, 0, US(hfbE), US(w_qkv3), ws + b_qkv3, nullptr, 0, US(qp),
     1152, 2304, 768, 768, 768, 2304, 0, 0, 0, 0, 1, 1.f);
  // content scores /48, batched over B=8 -> f32
  mg(stream, 64, 0, false, 0, US(qp), US(qp) + 768, nullptr, nullptr, 0, ws + p32_3,
     80, 80, 768, 2304, 2304, 128, 184320, 184320, 16384, 0, 8, 1.f / 48.f);
  // c2p (q @ posk^T) and p2c (k @ posq^T), batched
  mg(stream, 64, 0, false, 0, US(qp), US(qp) + (size_t)640 * 2304 + 768, nullptr, nullptr, 0, ws + c2p,
     640, 512, 768, 2304, 2304, 512, 768, -768, 327680, 0, 2, 1.f);
  // masked softmax -> bf16 probs
  deb3_kernel<<<160, 256, 0, stream>>>(ws + p32_3, ws + c2p, ws + p2c, mask, US(p3bf));
  // ctx = P @ V
  vtrans_kernel<<<dim3(12, 8), 256, 0, stream>>>(US(qp) + 1536, US(vt3b), 80, 2304, 184320, 98304);
  mg(stream, 64, 0, true, 0, US(p3bf), US(vt3b), nullptr, nullptr, 0, US(ctx3b),
     80, 768, 128, 128, 128, 768, 16384, 98304, 61440, 0, 8, 1.f);
  // attention output + residual(hf) -> t3 f32
  mg(stream, 64, 0, false, 2, US(ctx3b), US(w_ao), dao_b, ws + hf, 768, ws + t3,
     640, 768, 768, 768, 768, 768, 0, 0, 0, 0, 1, 1.f);
  ln_kernel<0, 0><<<160, 256, 0, stream>>>(ws + t3, nullptr,
      da_ln_g, da_ln_b, ws + h3, US(h3b), 640, 1e-7f);
  // FFN (exact gelu)
  mg(stream, 64, 2, true, 0, US(h3b), US(w_di), di_b, nullptr, 0, US(interb),
     640, 3072, 768, 768, 768, 3072, 0, 0, 0, 0, 1, 1.f);
  // do projection + residual(h3) -> t4 f32
  mg(stream, 64, 0, false, 2, US(interb), US(w_do), do_b, ws + h3, 768, ws + t4,
     640, 768, 3072, 3072, 3072, 768, 0, 0, 0, 0, 1, 1.f);
  ln_kernel<0, 0><<<160, 256, 0, stream>>>(ws + t4, nullptr,
      do_ln_g, do_ln_b, ws + h4, nullptr, 640, 1e-7f);
  meanF_kernel<<<8, 192, 0, stream>>>(ws + h4, ws + hm);
  head_kernel<<<dim3(250, 8), 64, 0, stream>>>(ws + hm, head_w, head_b, out);
}

// Round 12
// 1910.828 us; speedup vs baseline: 1.0969x; 1.0230x over previous
//
#include <hip/hip_runtime.h>

using short8v = __attribute__((ext_vector_type(8))) short;
using float4v = __attribute__((ext_vector_type(4))) float;

__device__ __forceinline__ unsigned short f2bf(float f) {
  unsigned int u = __float_as_uint(f);
  u += 0x7FFF + ((u >> 16) & 1);
  return (unsigned short)(u >> 16);
}
__device__ __forceinline__ float bf2f(unsigned short u) {
  return __uint_as_float((unsigned int)u << 16);
}

// ------------------------------------------------------------------
// bf16 MFMA GEMM, reg-staged + prefetch + LDS XOR swizzle.
// C = act(alpha*A.B^T + bias); A [M][K] bf16, B [N][K] bf16.
// 128x128 tile, BK=64, 4 waves (2x2 quadrants). K % 64 == 0.
// Batched via blockIdx.z (sA/sB/sC/sBias element strides).
// ------------------------------------------------------------------
__device__ __forceinline__ int swz(int row, int c) {
  return row * 64 + (c ^ ((row & 7) << 3));
}

template<int ACT, bool OUTBF>
__global__ __launch_bounds__(256) void gemm_mfma(
    const unsigned short* __restrict__ A, const unsigned short* __restrict__ B,
    const float* __restrict__ bias, void* __restrict__ Cv,
    int M, int N, int K, int lda, int ldb, int ldc,
    long long sA, long long sB, long long sC, long long sBias, float alpha)
{
  A += (long long)blockIdx.z * sA;
  B += (long long)blockIdx.z * sB;
  if (bias) bias += (long long)blockIdx.z * sBias;
  const int m0 = blockIdx.y * 128, n0 = blockIdx.x * 128;

  __shared__ __align__(16) unsigned short As[128 * 64];
  __shared__ __align__(16) unsigned short Bs[128 * 64];

  const int tid = threadIdx.x;
  const int w = tid >> 6, lane = tid & 63;
  const int wr = w >> 1, wc = w & 1;

  // staging: tile = 1024 chunks of 8 elems; thread covers 4 rows r0+32i, col c8
  const int r0 = tid >> 3;            // 0..31
  const int c8 = (tid & 7) * 8;       // 0,8,..,56
  int ra[4], rb[4], soff[4];
  #pragma unroll
  for (int i = 0; i < 4; ++i) {
    int r = m0 + r0 + i * 32; ra[i] = r < M - 1 ? r : M - 1;
    int q = n0 + r0 + i * 32; rb[i] = q < N - 1 ? q : N - 1;
    soff[i] = swz(r0 + i * 32, c8);
  }

  const int fr = lane & 15;
  const int fk = (lane >> 4) * 8;     // 0,8,16,24

  float4v acc[4][4] = {};

  short8v pa[4], pb[4];
  #pragma unroll
  for (int i = 0; i < 4; ++i) {
    pa[i] = *(const short8v*)(A + (long long)ra[i] * lda + c8);
    pb[i] = *(const short8v*)(B + (long long)rb[i] * ldb + c8);
  }

  for (int k0 = 0; k0 < K; k0 += 64) {
    __syncthreads();                  // prior iter's LDS reads done
    #pragma unroll
    for (int i = 0; i < 4; ++i) {
      *(short8v*)&As[soff[i]] = pa[i];
      *(short8v*)&Bs[soff[i]] = pb[i];
    }
    __syncthreads();
    if (k0 + 64 < K) {                // issue next tile early; drains next iter
      #pragma unroll
      for (int i = 0; i < 4; ++i) {
        pa[i] = *(const short8v*)(A + (long long)ra[i] * lda + k0 + 64 + c8);
        pb[i] = *(const short8v*)(B + (long long)rb[i] * ldb + k0 + 64 + c8);
      }
    }
    #pragma unroll
    for (int kk = 0; kk < 2; ++kk) {
      short8v a[4], b[4];
      #pragma unroll
      for (int i = 0; i < 4; ++i) {
        a[i] = *(const short8v*)&As[swz(wr * 64 + i * 16 + fr, kk * 32 + fk)];
        b[i] = *(const short8v*)&Bs[swz(wc * 64 + i * 16 + fr, kk * 32 + fk)];
      }
      #pragma unroll
      for (int mi = 0; mi < 4; ++mi)
        #pragma unroll
        for (int ni = 0; ni < 4; ++ni)
          acc[mi][ni] = __builtin_amdgcn_mfma_f32_16x16x32_bf16(a[mi], b[ni], acc[mi][ni], 0, 0, 0);
    }
  }

  // epilogue: C/D layout col=lane&15, row=(lane>>4)*4+reg  [m89/m91]
  const int ccol0 = n0 + wc * 64 + (lane & 15);
  const int crow0 = m0 + wr * 64 + (lane >> 4) * 4;
  float* Cf = (float*)Cv + (long long)blockIdx.z * sC;
  unsigned short* Cb = (unsigned short*)Cv + (long long)blockIdx.z * sC;
  #pragma unroll
  for (int ni = 0; ni < 4; ++ni) {
    const int col = ccol0 + ni * 16;
    if (col >= N) continue;
    const float bs = bias ? bias[col] : 0.f;
    #pragma unroll
    for (int mi = 0; mi < 4; ++mi) {
      #pragma unroll
      for (int r = 0; r < 4; ++r) {
        const int row = crow0 + mi * 16 + r;
        if (row >= M) continue;
        float v = acc[mi][ni][r] * alpha + bs;
        if (ACT == 1) v = fmaxf(v, 0.f);
        if (ACT == 2) v = 0.5f * v * (1.f + erff(v * 0.70710678118654752f));
        if (OUTBF) Cb[(long long)row * ldc + col] = f2bf(v);
        else       Cf[(long long)row * ldc + col] = v;
      }
    }
  }
}

static void mgemm(hipStream_t st, int act, bool outbf,
                  const unsigned short* A, const unsigned short* B,
                  const float* bias, void* C,
                  int M, int N, int K, int lda, int ldb, int ldc,
                  long long sA, long long sB, long long sC, long long sBias,
                  int bat, float alpha)
{
  dim3 grid((N + 127) / 128, (M + 127) / 128, bat);
  dim3 blk(256);
  if (outbf) {
    if (act == 1)      gemm_mfma<1, true ><<<grid, blk, 0, st>>>(A, B, bias, C, M, N, K, lda, ldb, ldc, sA, sB, sC, sBias, alpha);
    else if (act == 2) gemm_mfma<2, true ><<<grid, blk, 0, st>>>(A, B, bias, C, M, N, K, lda, ldb, ldc, sA, sB, sC, sBias, alpha);
    else               gemm_mfma<0, true ><<<grid, blk, 0, st>>>(A, B, bias, C, M, N, K, lda, ldb, ldc, sA, sB, sC, sBias, alpha);
  } else {
    gemm_mfma<0, false><<<grid, blk, 0, st>>>(A, B, bias, C, M, N, K, lda, ldb, ldc, sA, sB, sC, sBias, alpha);
  }
}

// ------------------------------------------------------------------
// fused f32 -> bf16 weight conversion (all tensors in one dispatch)
// ------------------------------------------------------------------
struct ConvArgs {
  const float* s[10];
  unsigned short* d[10];
  long long off[11];
};
__global__ __launch_bounds__(256) void convall_kernel(ConvArgs a, long long tot)
{
  const long long i = ((long long)blockIdx.x * 256 + threadIdx.x) * 4;
  if (i >= tot) return;
  int t = 0;
  while (i >= a.off[t + 1]) ++t;
  const long long j = i - a.off[t];
  const float4 v = *(const float4*)(a.s[t] + j);
  const unsigned int lo = (unsigned int)f2bf(v.x) | ((unsigned int)f2bf(v.y) << 16);
  const unsigned int hi = (unsigned int)f2bf(v.z) | ((unsigned int)f2bf(v.w) << 16);
  *(uint2*)(a.d[t] + j) = make_uint2(lo, hi);
}

// ------------------------------------------------------------------
// stage 1: wave-per-token embeddings + LN(256) x2 + pos projection
// ------------------------------------------------------------------
__global__ __launch_bounds__(256) void embed_kernel(
    const int* __restrict__ tids, const int* __restrict__ lids,
    const float* __restrict__ xs, const float* __restrict__ ys, const float* __restrict__ zs,
    const float* __restrict__ temb, const float* __restrict__ lemb,
    const float* __restrict__ tg, const float* __restrict__ tb,
    const float* __restrict__ lg, const float* __restrict__ lb,
    const float* __restrict__ pw, const float* __restrict__ pb,
    unsigned short* __restrict__ hb)
{
  const int tok = blockIdx.x * 4 + (threadIdx.x >> 6);
  const int lane = threadIdx.x & 63;
  const int e0 = lane * 4;
  const int ti = tids[tok], li = lids[tok];
  float4 tv = make_float4(0.f, 0.f, 0.f, 0.f);
  float4 lv = make_float4(0.f, 0.f, 0.f, 0.f);
  if (ti != 0) tv = *(const float4*)(temb + ti * 256 + e0);
  if (li != 0) lv = *(const float4*)(lemb + li * 256 + e0);

  float s0 = tv.x + tv.y + tv.z + tv.w;
  float s1 = tv.x * tv.x + tv.y * tv.y + tv.z * tv.z + tv.w * tv.w;
  float s2 = lv.x + lv.y + lv.z + lv.w;
  float s3 = lv.x * lv.x + lv.y * lv.y + lv.z * lv.z + lv.w * lv.w;
  #pragma unroll
  for (int off = 32; off > 0; off >>= 1) {
    s0 += __shfl_xor(s0, off, 64);
    s1 += __shfl_xor(s1, off, 64);
    s2 += __shfl_xor(s2, off, 64);
    s3 += __shfl_xor(s3, off, 64);
  }
  const float mt = s0 * (1.f / 256.f), vt = s1 * (1.f / 256.f) - mt * mt;
  const float ml = s2 * (1.f / 256.f), vl = s3 * (1.f / 256.f) - ml * ml;
  const float rt = rsqrtf(vt + 1e-5f), rl = rsqrtf(vl + 1e-5f);

  const float4 tg4 = *(const float4*)(tg + e0), tb4 = *(const float4*)(tb + e0);
  const float4 lg4 = *(const float4*)(lg + e0), lb4 = *(const float4*)(lb + e0);
  const size_t base = (size_t)tok * 768;
  ushort4 o;
  o.x = f2bf((tv.x - mt) * rt * tg4.x + tb4.x);
  o.y = f2bf((tv.y - mt) * rt * tg4.y + tb4.y);
  o.z = f2bf((tv.z - mt) * rt * tg4.z + tb4.z);
  o.w = f2bf((tv.w - mt) * rt * tg4.w + tb4.w);
  *(ushort4*)(hb + base + e0) = o;
  o.x = f2bf((lv.x - ml) * rl * lg4.x + lb4.x);
  o.y = f2bf((lv.y - ml) * rl * lg4.y + lb4.y);
  o.z = f2bf((lv.z - ml) * rl * lg4.z + lb4.z);
  o.w = f2bf((lv.w - ml) * rl * lg4.w + lb4.w);
  *(ushort4*)(hb + base + 256 + e0) = o;

  const float X = xs[tok], Y = ys[tok], Z = zs[tok];
  const float4 w0 = *(const float4*)(pw + 12 * lane);
  const float4 w1 = *(const float4*)(pw + 12 * lane + 4);
  const float4 w2 = *(const float4*)(pw + 12 * lane + 8);
  const float4 pb4 = *(const float4*)(pb + e0);
  o.x = f2bf(w0.x * X + w0.y * Y + w0.z * Z + pb4.x);
  o.y = f2bf(w0.w * X + w1.x * Y + w1.y * Z + pb4.y);
  o.z = f2bf(w1.z * X + w1.w * Y + w2.x * Z + pb4.z);
  o.w = f2bf(w2.y * X + w2.z * Y + w2.w * Z + pb4.w);
  *(ushort4*)(hb + base + 512 + e0) = o;
}

// ------------------------------------------------------------------
// LayerNorm, wave-per-row, D=768. XBF/RBF select input dtypes.
// ------------------------------------------------------------------
template<int XBF, int RBF>
__global__ __launch_bounds__(256) void ln_kernel(
    const void* __restrict__ x, const void* __restrict__ res,
    const float* __restrict__ g, const float* __restrict__ b,
    float* __restrict__ yf, unsigned short* __restrict__ yb,
    int nrows, float eps)
{
  const int row = blockIdx.x * 4 + (threadIdx.x >> 6);
  if (row >= nrows) return;
  const int lane = threadIdx.x & 63;
  const size_t base = (size_t)row * 768;
  const int e0 = lane * 12;
  float v[12];
  #pragma unroll
  for (int j = 0; j < 3; ++j) {
    if (XBF) {
      const ushort4 u = *(const ushort4*)((const unsigned short*)x + base + e0 + 4 * j);
      v[4*j+0] = bf2f(u.x); v[4*j+1] = bf2f(u.y); v[4*j+2] = bf2f(u.z); v[4*j+3] = bf2f(u.w);
    } else {
      const float4 f = *(const float4*)((const float*)x + base + e0 + 4 * j);
      v[4*j+0] = f.x; v[4*j+1] = f.y; v[4*j+2] = f.z; v[4*j+3] = f.w;
    }
  }
  if (res) {
    #pragma unroll
    for (int j = 0; j < 3; ++j) {
      if (RBF) {
        const ushort4 u = *(const ushort4*)((const unsigned short*)res + base + e0 + 4 * j);
        v[4*j+0] += bf2f(u.x); v[4*j+1] += bf2f(u.y); v[4*j+2] += bf2f(u.z); v[4*j+3] += bf2f(u.w);
      } else {
        const float4 f = *(const float4*)((const float*)res + base + e0 + 4 * j);
        v[4*j+0] += f.x; v[4*j+1] += f.y; v[4*j+2] += f.z; v[4*j+3] += f.w;
      }
    }
  }
  float s = 0.f, ss = 0.f;
  #pragma unroll
  for (int j = 0; j < 12; ++j) { s += v[j]; ss += v[j] * v[j]; }
  #pragma unroll
  for (int off = 32; off > 0; off >>= 1) {
    s += __shfl_xor(s, off, 64);
    ss += __shfl_xor(ss, off, 64);
  }
  const float mean = s * (1.f / 768.f);
  const float rstd = rsqrtf(ss * (1.f / 768.f) - mean * mean + eps);
  #pragma unroll
  for (int j = 0; j < 3; ++j) {
    const float4 g4 = *(const float4*)(g + e0 + 4 * j);
    const float4 b4 = *(const float4*)(b + e0 + 4 * j);
    float o0 = (v[4*j+0] - mean) * rstd * g4.x + b4.x;
    float o1 = (v[4*j+1] - mean) * rstd * g4.y + b4.y;
    float o2 = (v[4*j+2] - mean) * rstd * g4.z + b4.z;
    float o3 = (v[4*j+3] - mean) * rstd * g4.w + b4.w;
    if (yf) *(float4*)(yf + base + e0 + 4 * j) = make_float4(o0, o1, o2, o3);
    if (yb) {
      ushort4 u; u.x = f2bf(o0); u.y = f2bf(o1); u.z = f2bf(o2); u.w = f2bf(o3);
      *(ushort4*)(yb + base + e0 + 4 * j) = u;
    }
  }
}

// ------------------------------------------------------------------
// V transpose: v[b][k][rs-strided] (k<Lk) -> vt[b][d][128] zero-padded
// ------------------------------------------------------------------
__global__ __launch_bounds__(256) void vtrans_kernel(
    const unsigned short* __restrict__ v, unsigned short* __restrict__ vt,
    int Lk, int rs, long long sIn, long long sOut)
{
  __shared__ unsigned short s[64][132];
  const int b = blockIdx.y, d0 = blockIdx.x * 64;
  const unsigned short* vb = v + (long long)b * sIn;
  unsigned short* ob = vt + (long long)b * sOut;
  for (int idx = threadIdx.x; idx < 128 * 64; idx += 256) {
    const int k = idx >> 6, dd = idx & 63;
    s[dd][k] = (k < Lk) ? vb[(long long)k * rs + d0 + dd] : (unsigned short)0;
  }
  __syncthreads();
  for (int idx = threadIdx.x; idx < 64 * 128; idx += 256) {
    const int dd = idx >> 7, k = idx & 127;
    ob[(long long)(d0 + dd) * 128 + k] = s[dd][k];
  }
}

// ------------------------------------------------------------------
// stage-2 softmax, wave-per-row: rows [c][q<100], width 100 -> 128 pad
// ------------------------------------------------------------------
__global__ __launch_bounds__(256) void sm2_kernel(
    const float* __restrict__ P32, unsigned short* __restrict__ Pbf, int nrows)
{
  const int rid = blockIdx.x * 4 + (threadIdx.x >> 6);
  if (rid >= nrows) return;
  const int z = rid / 100, q = rid - z * 100;
  const int lane = threadIdx.x & 63;
  const float* row = P32 + (size_t)z * 16384 + (size_t)q * 128;
  unsigned short* orow = Pbf + (size_t)z * 16384 + (size_t)q * 128;
  const float v0 = row[lane];
  const float v1 = (lane + 64 < 100) ? row[lane + 64] : -3.4e38f;
  float m = fmaxf(v0, v1);
  #pragma unroll
  for (int off = 32; off > 0; off >>= 1) m = fmaxf(m, __shfl_xor(m, off, 64));
  const float e0 = expf(v0 - m);
  const float e1 = (lane + 64 < 100) ? expf(v1 - m) : 0.f;
  float s = e0 + e1;
  #pragma unroll
  for (int off = 32; off > 0; off >>= 1) s += __shfl_xor(s, off, 64);
  const float inv = 1.f / s;
  orow[lane] = f2bf(e0 * inv);
  orow[lane + 64] = (lane + 64 < 100) ? f2bf(e1 * inv) : (unsigned short)0;
}

// ------------------------------------------------------------------
// stage-3 masked deberta softmax, wave-per-row -> bf16 [8][128][128]
// ------------------------------------------------------------------
__global__ __launch_bounds__(256) void deb3_kernel(
    const float* __restrict__ sc,   // [8][128][128]
    const float* __restrict__ c2p,  // [640][512]
    const float* __restrict__ p2c,  // [640][512]
    const int* __restrict__ mask,   // [8][80][100]
    unsigned short* __restrict__ probs) // [8][128][128]
{
  const int rid = blockIdx.x * 4 + (threadIdx.x >> 6);
  if (rid >= 640) return;
  const int b = rid / 80, q = rid - b * 80;
  const int lane = threadIdx.x & 63;
  const bool mq = mask[(size_t)rid * 100] > 0;
  float v0 = -3.4e38f, v1 = -3.4e38f;
  bool val0 = false, val1 = false;
  {
    const int k = lane;            // k < 80 always
    const bool mk = mask[(size_t)(b * 80 + k) * 100] > 0;
    val0 = mq && mk;
    const int r = 256 + q - k;
    if (val0)
      v0 = sc[(size_t)b * 16384 + (size_t)q * 128 + k] +
           (c2p[(size_t)rid * 512 + r] + p2c[(size_t)(b * 80 + k) * 512 + r]) * (1.f / 48.f);
  }
  if (lane + 64 < 80) {
    const int k = lane + 64;
    const bool mk = mask[(size_t)(b * 80 + k) * 100] > 0;
    val1 = mq && mk;
    const int r = 256 + q - k;
    if (val1)
      v1 = sc[(size_t)b * 16384 + (size_t)q * 128 + k] +
           (c2p[(size_t)rid * 512 + r] + p2c[(size_t)(b * 80 + k) * 512 + r]) * (1.f / 48.f);
  }
  float m = fmaxf(v0, v1);
  #pragma unroll
  for (int off = 32; off > 0; off >>= 1) m = fmaxf(m, __shfl_xor(m, off, 64));
  const float e0 = val0 ? expf(v0 - m) : 0.f;
  const float e1 = val1 ? expf(v1 - m) : 0.f;
  float s = e0 + e1;
  #pragma unroll
  for (int off = 32; off > 0; off >>= 1) s += __shfl_xor(s, off, 64);
  const float inv = (s > 0.f) ? 1.f / s : 0.f;
  unsigned short* orow = probs + (size_t)b * 16384 + (size_t)q * 128;
  orow[lane] = val0 ? f2bf(e0 * inv) : (unsigned short)0;
  orow[lane + 64] = val1 ? f2bf(e1 * inv) : (unsigned short)0;
}

// ------------------------------------------------------------------
// means
// ------------------------------------------------------------------
__global__ __launch_bounds__(192) void meanL_kernel(
    const unsigned short* __restrict__ hb, float* __restrict__ hf,
    unsigned short* __restrict__ hfb)
{
  const int bf = blockIdx.x;            // 640
  const int d0 = threadIdx.x * 4;       // 0..764
  float4 acc = make_float4(0.f, 0.f, 0.f, 0.f);
  for (int l = 0; l < 100; ++l) {
    const ushort4 u = *(const ushort4*)(hb + ((size_t)bf * 100 + l) * 768 + d0);
    acc.x += bf2f(u.x); acc.y += bf2f(u.y); acc.z += bf2f(u.z); acc.w += bf2f(u.w);
  }
  acc.x *= 0.01f; acc.y *= 0.01f; acc.z *= 0.01f; acc.w *= 0.01f;
  *(float4*)(hf + (size_t)bf * 768 + d0) = acc;
  ushort4 o; o.x = f2bf(acc.x); o.y = f2bf(acc.y); o.z = f2bf(acc.z); o.w = f2bf(acc.w);
  *(ushort4*)(hfb + (size_t)bf * 768 + d0) = o;
}

__global__ __launch_bounds__(192) void meanF_kernel(const float* __restrict__ h4, float* __restrict__ hm)
{
  const int b = blockIdx.x;             // 8
  const int d0 = threadIdx.x * 4;
  float4 acc = make_float4(0.f, 0.f, 0.f, 0.f);
  for (int f = 0; f < 80; ++f) {
    const float4 u = *(const float4*)(h4 + ((size_t)b * 80 + f) * 768 + d0);
    acc.x += u.x; acc.y += u.y; acc.z += u.z; acc.w += u.w;
  }
  const float k = 1.f / 80.f;
  *(float4*)(hm + (size_t)b * 768 + d0) = make_float4(acc.x * k, acc.y * k, acc.z * k, acc.w * k);
}

// ------------------------------------------------------------------
// head: out[b][n] = hm[b] . head_w[n] + head_b[n]
// ------------------------------------------------------------------
__global__ __launch_bounds__(64) void head_kernel(
    const float* __restrict__ hm, const float* __restrict__ w,
    const float* __restrict__ bias, float* __restrict__ out)
{
  const int n = blockIdx.x, b = blockIdx.y;
  const float* x = hm + (size_t)b * 768;
  const float* wn = w + (size_t)n * 768;
  float s = 0.f;
  for (int i = threadIdx.x * 4; i < 768; i += 256) {
    const float4 xv = *(const float4*)(x + i);
    const float4 wv = *(const float4*)(wn + i);
    s += xv.x * wv.x + xv.y * wv.y + xv.z * wv.z + xv.w * wv.w;
  }
  #pragma unroll
  for (int off = 32; off > 0; off >>= 1) s += __shfl_down(s, off, 64);
  if (threadIdx.x == 0) out[(size_t)b * 250 + n] = s + bias[n];
}

// ------------------------------------------------------------------
// host
// ------------------------------------------------------------------
extern "C" void kernel_launch(void* const* d_in, const int* in_sizes, int n_in,
                              void* d_out, int out_size, void* d_ws, size_t ws_size,
                              hipStream_t stream)
{
  const int*   type_ids   = (const int*)  d_in[0];
  const int*   lm_ids     = (const int*)  d_in[1];
  const float* xs         = (const float*)d_in[2];
  const float* ys         = (const float*)d_in[3];
  const float* zs         = (const float*)d_in[4];
  const int*   mask       = (const int*)  d_in[5];
  const float* type_emb   = (const float*)d_in[6];
  const float* lm_emb     = (const float*)d_in[7];
  const float* type_ln_g  = (const float*)d_in[8];
  const float* type_ln_b  = (const float*)d_in[9];
  const float* lm_ln_g    = (const float*)d_in[10];
  const float* lm_ln_b    = (const float*)d_in[11];
  const float* pos_w      = (const float*)d_in[12];
  const float* pos_b      = (const float*)d_in[13];
  const float* lt_in_w    = (const float*)d_in[14];
  const float* lt_in_b    = (const float*)d_in[15];
  const float* lt_out_w   = (const float*)d_in[16];
  const float* lt_out_b   = (const float*)d_in[17];
  const float* lt_ln1_g   = (const float*)d_in[18];
  const float* lt_ln1_b   = (const float*)d_in[19];
  const float* lt_ff1_w   = (const float*)d_in[20];
  const float* lt_ff1_b   = (const float*)d_in[21];
  const float* lt_ff2_w   = (const float*)d_in[22];
  const float* lt_ff2_b   = (const float*)d_in[23];
  const float* lt_ln2_g   = (const float*)d_in[24];
  const float* lt_ln2_b   = (const float*)d_in[25];
  const float* rel_emb    = (const float*)d_in[26];
  const float* rel_ln_g   = (const float*)d_in[27];
  const float* rel_ln_b   = (const float*)d_in[28];
  const float* dq_w       = (const float*)d_in[29];
  const float* dq_b       = (const float*)d_in[30];
  const float* dk_w       = (const float*)d_in[31];
  const float* dk_b       = (const float*)d_in[32];
  const float* dv_w       = (const float*)d_in[33];
  const float* dv_b       = (const float*)d_in[34];
  const float* dao_w      = (const float*)d_in[35];
  const float* dao_b      = (const float*)d_in[36];
  const float* da_ln_g    = (const float*)d_in[37];
  const float* da_ln_b    = (const float*)d_in[38];
  const float* di_w       = (const float*)d_in[39];
  const float* di_b       = (const float*)d_in[40];
  const float* do_w       = (const float*)d_in[41];
  const float* do_b       = (const float*)d_in[42];
  const float* do_ln_g    = (const float*)d_in[43];
  const float* do_ln_b    = (const float*)d_in[44];
  const float* head_w     = (const float*)d_in[45];
  const float* head_b     = (const float*)d_in[46];
  float* out = (float*)d_out;
  float* ws  = (float*)d_ws;

  const float inv_sqrt_d = 0.03608439182435161f;  // 1/sqrt(768)
  const long long W2 = 768 * 768;

  auto rnd = [](size_t x) { return (x + 63) & ~(size_t)63; };
  const size_t ws_floats = ws_size / sizeof(float);

  // ---- persistent region (float units) ----
  size_t o = 0;
  const size_t offHB = o; o += rnd((size_t)64000 * 768 / 2);   // h bf16
  auto woff = [&](size_t elems) { size_t r = o; o += rnd(elems / 2); return r; };
  const size_t w_in   = woff((size_t)2304 * 768);
  const size_t w_out  = woff((size_t)768 * 768);
  const size_t w_f1   = woff((size_t)768 * 768);
  const size_t w_f2   = woff((size_t)768 * 768);
  const size_t w_qkv3 = woff((size_t)2304 * 768);   // dq|dk|dv
  const size_t w_ao   = woff((size_t)768 * 768);
  const size_t w_di   = woff((size_t)3072 * 768);
  const size_t w_do   = woff((size_t)768 * 3072);
  const size_t b_qkv3 = o; o += rnd(2304);          // f32 concat bias
  const size_t scratch0 = o;

  // ---- stage-3 scratch need ----
  size_t s3need = 0;
  {
    size_t t = 0;
    t += rnd((size_t)640 * 768);         // hf f32
    t += rnd((size_t)640 * 768 / 2);     // hfb
    t += rnd((size_t)640 * 2304 / 2);    // qkv3b
    t += rnd((size_t)512 * 768 / 2);     // rlnb
    t += rnd((size_t)512 * 1536 / 2);    // posb
    t += 2 * (size_t)640 * 512;          // c2p,p2c f32 (contiguous)
    t += rnd((size_t)8 * 16384);         // p32_3
    t += rnd((size_t)8 * 16384 / 2);     // p3bf
    t += rnd((size_t)8 * 98304 / 2);     // vt3
    t += rnd((size_t)640 * 768 / 2);     // ctx3b
    t += 2 * rnd((size_t)640 * 768);     // t3,h3
    t += rnd((size_t)640 * 768 / 2);     // h3b
    t += rnd((size_t)640 * 3072 / 2);    // interb
    t += 2 * rnd((size_t)640 * 768);     // t4,h4
    t += rnd((size_t)8 * 768);           // hm
    s3need = t;
  }

  // ---- pick stage-2 chunk size (all bf16 intermediates) ----
  auto chunk_need = [&](int c) {
    const size_t R = (size_t)c * 100;
    size_t t = 0;
    t += rnd(R * 2304 / 2);             // qkv
    t += 4 * rnd(R * 768 / 2);          // ctx, t1b, h1b, ffo
    t += rnd((size_t)c * 98304 / 2);    // vt
    t += rnd((size_t)c * 16384);        // p32 f32
    t += rnd((size_t)c * 16384 / 2);    // pbf
    return t;
  };
  int C = 1;
  {
    const int cands[] = {640, 320, 160, 80, 40, 20, 10, 5, 2, 1};
    for (int c : cands) {
      const size_t need = scratch0 + (chunk_need(c) > s3need ? chunk_need(c) : s3need);
      if (need <= ws_floats) { C = c; break; }
    }
  }
  const size_t R = (size_t)C * 100;

  // stage-2 chunk layout
  o = scratch0;
  const size_t qkvb = o; o += rnd(R * 2304 / 2);
  const size_t ctxb = o; o += rnd(R * 768 / 2);
  const size_t t1b  = o; o += rnd(R * 768 / 2);
  const size_t h1bb = o; o += rnd(R * 768 / 2);
  const size_t ffob = o; o += rnd(R * 768 / 2);
  const size_t vtb  = o; o += rnd((size_t)C * 98304 / 2);
  const size_t p32  = o; o += rnd((size_t)C * 16384);
  const size_t pbf  = o; o += rnd((size_t)C * 16384 / 2);

  auto US = [&](size_t foff) { return (unsigned short*)(ws + foff); };

  // ---------------- fused weight conversion ----------------
  {
    ConvArgs a;
    const float* srcs[10] = {lt_in_w, lt_out_w, lt_ff1_w, lt_ff2_w,
                             dq_w, dk_w, dv_w, dao_w, di_w, do_w};
    unsigned short* dsts[10] = {US(w_in), US(w_out), US(w_f1), US(w_f2),
                                US(w_qkv3), US(w_qkv3) + W2, US(w_qkv3) + 2 * W2,
                                US(w_ao), US(w_di), US(w_do)};
    const long long ns[10] = {2304 * 768, W2, W2, W2, W2, W2, W2, W2,
                              3072 * 768, 3072 * 768};
    long long tot = 0;
    for (int i = 0; i < 10; ++i) { a.s[i] = srcs[i]; a.d[i] = dsts[i]; a.off[i] = tot; tot += ns[i]; }
    a.off[10] = tot;
    convall_kernel<<<(unsigned)((tot / 4 + 255) / 256), 256, 0, stream>>>(a, tot);
  }
  // concat deberta qkv bias (f32)
  hipMemcpyAsync(ws + b_qkv3,        dq_b, 768 * sizeof(float), hipMemcpyDeviceToDevice, stream);
  hipMemcpyAsync(ws + b_qkv3 + 768,  dk_b, 768 * sizeof(float), hipMemcpyDeviceToDevice, stream);
  hipMemcpyAsync(ws + b_qkv3 + 1536, dv_b, 768 * sizeof(float), hipMemcpyDeviceToDevice, stream);

  // ---------------- stage 1 ----------------
  embed_kernel<<<16000, 256, 0, stream>>>(type_ids, lm_ids, xs, ys, zs,
      type_emb, lm_emb, type_ln_g, type_ln_b, lm_ln_g, lm_ln_b, pos_w, pos_b,
      US(offHB));

  // ---------------- stage 2 (chunked over sequences) ----------------
  for (int c0 = 0; c0 < 640; c0 += C) {
    unsigned short* hbc = US(offHB) + (size_t)c0 * 100 * 768;
    const int Rr = C * 100;
    // fused qkv
    mgemm(stream, 0, true, hbc, US(w_in), lt_in_b, US(qkvb),
          Rr, 2304, 768, 768, 768, 2304, 0, 0, 0, 0, 1, 1.f);
    // scores, batched per sequence
    mgemm(stream, 0, false, US(qkvb), US(qkvb) + 768, nullptr, ws + p32,
          100, 100, 768, 2304, 2304, 128, 230400, 230400, 16384, 0, C, inv_sqrt_d);
    sm2_kernel<<<(Rr + 3) / 4, 256, 0, stream>>>(ws + p32, US(pbf), Rr);
    vtrans_kernel<<<dim3(12, C), 256, 0, stream>>>(US(qkvb) + 1536, US(vtb), 100, 2304, 230400, 98304);
    mgemm(stream, 0, true, US(pbf), US(vtb), nullptr, US(ctxb),
          100, 768, 128, 128, 128, 768, 16384, 98304, 76800, 0, C, 1.f);
    // out projection (bf16)
    mgemm(stream, 0, true, US(ctxb), US(w_out), lt_out_b, US(t1b),
          Rr, 768, 768, 768, 768, 768, 0, 0, 0, 0, 1, 1.f);
    // h1 = LN(h + attn)
    ln_kernel<1, 1><<<(Rr + 3) / 4, 256, 0, stream>>>(hbc, US(t1b),
        lt_ln1_g, lt_ln1_b, nullptr, US(h1bb), Rr, 1e-5f);
    // ff
    mgemm(stream, 1, true, US(h1bb), US(w_f1), lt_ff1_b, US(ffob),
          Rr, 768, 768, 768, 768, 768, 0, 0, 0, 0, 1, 1.f);
    mgemm(stream, 0, true, US(ffob), US(w_f2), lt_ff2_b, US(t1b),
          Rr, 768, 768, 768, 768, 768, 0, 0, 0, 0, 1, 1.f);
    // h2 = LN(h1 + ff) -> back into h
    ln_kernel<1, 1><<<(Rr + 3) / 4, 256, 0, stream>>>(US(h1bb), US(t1b),
        lt_ln2_g, lt_ln2_b, nullptr, hbc, Rr, 1e-5f);
  }

  // ---------------- stage 3 layout ----------------
  o = scratch0;
  const size_t hf    = o; o += rnd((size_t)640 * 768);
  const size_t hfb   = o; o += rnd((size_t)640 * 768 / 2);
  const size_t qkv3b = o; o += rnd((size_t)640 * 2304 / 2);
  const size_t rlnb  = o; o += rnd((size_t)512 * 768 / 2);
  const size_t posb  = o; o += rnd((size_t)512 * 1536 / 2);
  const size_t c2p   = o; o += (size_t)640 * 512;
  const size_t p2c   = o; o += (size_t)640 * 512;
  const size_t p32_3 = o; o += rnd((size_t)8 * 16384);
  const size_t p3bf  = o; o += rnd((size_t)8 * 16384 / 2);
  const size_t vt3b  = o; o += rnd((size_t)8 * 98304 / 2);
  const size_t ctx3b = o; o += rnd((size_t)640 * 768 / 2);
  const size_t t3    = o; o += rnd((size_t)640 * 768);
  const size_t h3    = o; o += rnd((size_t)640 * 768);
  const size_t h3b   = o; o += rnd((size_t)640 * 768 / 2);
  const size_t interb= o; o += rnd((size_t)640 * 3072 / 2);
  const size_t t4    = o; o += rnd((size_t)640 * 768);
  const size_t h4    = o; o += rnd((size_t)640 * 768);
  const size_t hm    = o; o += rnd((size_t)8 * 768);

  meanL_kernel<<<640, 192, 0, stream>>>(US(offHB), ws + hf, US(hfb));
  // fused q|k|v projection
  mgemm(stream, 0, true, US(hfb), US(w_qkv3), ws + b_qkv3, US(qkv3b),
        640, 2304, 768, 768, 768, 2304, 0, 0, 0, 0, 1, 1.f);
  // rel embedding LN
  ln_kernel<0, 0><<<128, 256, 0, stream>>>(rel_emb, nullptr,
      rel_ln_g, rel_ln_b, nullptr, US(rlnb), 512, 1e-7f);
  // pos_k | pos_q (batched; z=0 uses dk, z=1 uses dq)
  mgemm(stream, 0, true, US(rlnb), US(w_qkv3) + W2, ws + b_qkv3 + 768, US(posb),
        512, 768, 768, 768, 768, 1536, 0, -W2, 768, -768, 2, 1.f);
  // content scores /48, batched over B=8
  mgemm(stream, 0, false, US(qkv3b), US(qkv3b) + 768, nullptr, ws + p32_3,
        80, 80, 768, 2304, 2304, 128, 184320, 184320, 16384, 0, 8, 1.f / 48.f);
  // c2p (q @ pos_k^T) and p2c (k @ pos_q^T), batched
  mgemm(stream, 0, false, US(qkv3b), US(posb), nullptr, ws + c2p,
        640, 512, 768, 2304, 1536, 512, 768, 768, 327680, 0, 2, 1.f);
  // masked softmax -> bf16 probs
  deb3_kernel<<<160, 256, 0, stream>>>(ws + p32_3, ws + c2p, ws + p2c, mask, US(p3bf));
  // ctx = P @ V
  vtrans_kernel<<<dim3(12, 8), 256, 0, stream>>>(US(qkv3b) + 1536, US(vt3b), 80, 2304, 184320, 98304);
  mgemm(stream, 0, true, US(p3bf), US(vt3b), nullptr, US(ctx3b),
        80, 768, 128, 128, 128, 768, 16384, 98304, 61440, 0, 8, 1.f);
  // attention output + LN
  mgemm(stream, 0, false, US(ctx3b), US(w_ao), dao_b, ws + t3,
        640, 768, 768, 768, 768, 768, 0, 0, 0, 0, 1, 1.f);
  ln_kernel<0, 0><<<160, 256, 0, stream>>>(ws + hf, ws + t3,
      da_ln_g, da_ln_b, ws + h3, US(h3b), 640, 1e-7f);
  // FFN (exact gelu) + LN
  mgemm(stream, 2, true, US(h3b), US(w_di), di_b, US(interb),
        640, 3072, 768, 768, 768, 3072, 0, 0, 0, 0, 1, 1.f);
  mgemm(stream, 0, false, US(interb), US(w_do), do_b, ws + t4,
        640, 768, 3072, 3072, 3072, 768, 0, 0, 0, 0, 1, 1.f);
  ln_kernel<0, 0><<<160, 256, 0, stream>>>(ws + h3, ws + t4,
      do_ln_g, do_ln_b, ws + h4, nullptr, 640, 1e-7f);
  // mean over frames + head
  meanF_kernel<<<8, 192, 0, stream>>>(ws + h4, ws + hm);
  head_kernel<<<dim3(250, 8), 64, 0, stream>>>(ws + hm, head_w, head_b, out);
}

// Round 13
// 1899.617 us; speedup vs baseline: 1.1034x; 1.0059x over previous
//
#include <hip/hip_runtime.h>

using short8v = __attribute__((ext_vector_type(8))) short;
using float4v = __attribute__((ext_vector_type(4))) float;

__device__ __forceinline__ unsigned short f2bf(float f) {
  unsigned int u = __float_as_uint(f);
  u += 0x7FFF + ((u >> 16) & 1);
  return (unsigned short)(u >> 16);
}
__device__ __forceinline__ float bf2f(unsigned short u) {
  return __uint_as_float((unsigned int)u << 16);
}

// ------------------------------------------------------------------
// bf16 MFMA GEMM, reg-staged + prefetch + LDS XOR swizzle.
// C = act(alpha*A.B^T + bias); A [M][K] bf16, B [N][K] bf16.
// 128x128 tile, BK=64, 4 waves (2x2 quadrants). K % 64 == 0.
// Batched via blockIdx.z (sA/sB/sC/sBias element strides).
// ------------------------------------------------------------------
__device__ __forceinline__ int swz(int row, int c) {
  return row * 64 + (c ^ ((row & 7) << 3));
}

template<int ACT, bool OUTBF>
__global__ __launch_bounds__(256) void gemm_mfma(
    const unsigned short* __restrict__ A, const unsigned short* __restrict__ B,
    const float* __restrict__ bias, void* __restrict__ Cv,
    int M, int N, int K, int lda, int ldb, int ldc,
    long long sA, long long sB, long long sC, long long sBias, float alpha)
{
  A += (long long)blockIdx.z * sA;
  B += (long long)blockIdx.z * sB;
  if (bias) bias += (long long)blockIdx.z * sBias;
  const int m0 = blockIdx.y * 128, n0 = blockIdx.x * 128;

  __shared__ __align__(16) unsigned short As[128 * 64];
  __shared__ __align__(16) unsigned short Bs[128 * 64];

  const int tid = threadIdx.x;
  const int w = tid >> 6, lane = tid & 63;
  const int wr = w >> 1, wc = w & 1;

  // staging: tile = 1024 chunks of 8 elems; thread covers 4 rows r0+32i, col c8
  const int r0 = tid >> 3;            // 0..31
  const int c8 = (tid & 7) * 8;       // 0,8,..,56
  int ra[4], rb[4], soff[4];
  #pragma unroll
  for (int i = 0; i < 4; ++i) {
    int r = m0 + r0 + i * 32; ra[i] = r < M - 1 ? r : M - 1;
    int q = n0 + r0 + i * 32; rb[i] = q < N - 1 ? q : N - 1;
    soff[i] = swz(r0 + i * 32, c8);
  }

  const int fr = lane & 15;
  const int fk = (lane >> 4) * 8;     // 0,8,16,24

  float4v acc[4][4] = {};

  short8v pa[4], pb[4];
  #pragma unroll
  for (int i = 0; i < 4; ++i) {
    pa[i] = *(const short8v*)(A + (long long)ra[i] * lda + c8);
    pb[i] = *(const short8v*)(B + (long long)rb[i] * ldb + c8);
  }

  for (int k0 = 0; k0 < K; k0 += 64) {
    __syncthreads();                  // prior iter's LDS reads done
    #pragma unroll
    for (int i = 0; i < 4; ++i) {
      *(short8v*)&As[soff[i]] = pa[i];
      *(short8v*)&Bs[soff[i]] = pb[i];
    }
    __syncthreads();
    if (k0 + 64 < K) {                // issue next tile early; drains next iter
      #pragma unroll
      for (int i = 0; i < 4; ++i) {
        pa[i] = *(const short8v*)(A + (long long)ra[i] * lda + k0 + 64 + c8);
        pb[i] = *(const short8v*)(B + (long long)rb[i] * ldb + k0 + 64 + c8);
      }
    }
    #pragma unroll
    for (int kk = 0; kk < 2; ++kk) {
      short8v a[4], b[4];
      #pragma unroll
      for (int i = 0; i < 4; ++i) {
        a[i] = *(const short8v*)&As[swz(wr * 64 + i * 16 + fr, kk * 32 + fk)];
        b[i] = *(const short8v*)&Bs[swz(wc * 64 + i * 16 + fr, kk * 32 + fk)];
      }
      #pragma unroll
      for (int mi = 0; mi < 4; ++mi)
        #pragma unroll
        for (int ni = 0; ni < 4; ++ni)
          acc[mi][ni] = __builtin_amdgcn_mfma_f32_16x16x32_bf16(a[mi], b[ni], acc[mi][ni], 0, 0, 0);
    }
  }

  // epilogue: C/D layout col=lane&15, row=(lane>>4)*4+reg  [m89/m91]
  const int ccol0 = n0 + wc * 64 + (lane & 15);
  const int crow0 = m0 + wr * 64 + (lane >> 4) * 4;
  float* Cf = (float*)Cv + (long long)blockIdx.z * sC;
  unsigned short* Cb = (unsigned short*)Cv + (long long)blockIdx.z * sC;
  #pragma unroll
  for (int ni = 0; ni < 4; ++ni) {
    const int col = ccol0 + ni * 16;
    if (col >= N) continue;
    const float bs = bias ? bias[col] : 0.f;
    #pragma unroll
    for (int mi = 0; mi < 4; ++mi) {
      #pragma unroll
      for (int r = 0; r < 4; ++r) {
        const int row = crow0 + mi * 16 + r;
        if (row >= M) continue;
        float v = acc[mi][ni][r] * alpha + bs;
        if (ACT == 1) v = fmaxf(v, 0.f);
        if (ACT == 2) v = 0.5f * v * (1.f + erff(v * 0.70710678118654752f));
        if (OUTBF) Cb[(long long)row * ldc + col] = f2bf(v);
        else       Cf[(long long)row * ldc + col] = v;
      }
    }
  }
}

static void mgemm(hipStream_t st, int act, bool outbf,
                  const unsigned short* A, const unsigned short* B,
                  const float* bias, void* C,
                  int M, int N, int K, int lda, int ldb, int ldc,
                  long long sA, long long sB, long long sC, long long sBias,
                  int bat, float alpha)
{
  dim3 grid((N + 127) / 128, (M + 127) / 128, bat);
  dim3 blk(256);
  if (outbf) {
    if (act == 1)      gemm_mfma<1, true ><<<grid, blk, 0, st>>>(A, B, bias, C, M, N, K, lda, ldb, ldc, sA, sB, sC, sBias, alpha);
    else if (act == 2) gemm_mfma<2, true ><<<grid, blk, 0, st>>>(A, B, bias, C, M, N, K, lda, ldb, ldc, sA, sB, sC, sBias, alpha);
    else               gemm_mfma<0, true ><<<grid, blk, 0, st>>>(A, B, bias, C, M, N, K, lda, ldb, ldc, sA, sB, sC, sBias, alpha);
  } else {
    gemm_mfma<0, false><<<grid, blk, 0, st>>>(A, B, bias, C, M, N, K, lda, ldb, ldc, sA, sB, sC, sBias, alpha);
  }
}

// ------------------------------------------------------------------
// fused f32 -> bf16 weight conversion (all tensors in one dispatch)
// ------------------------------------------------------------------
struct ConvArgs {
  const float* s[10];
  unsigned short* d[10];
  long long off[11];
};
__global__ __launch_bounds__(256) void convall_kernel(ConvArgs a, long long tot)
{
  const long long i = ((long long)blockIdx.x * 256 + threadIdx.x) * 4;
  if (i >= tot) return;
  int t = 0;
  while (i >= a.off[t + 1]) ++t;
  const long long j = i - a.off[t];
  const float4 v = *(const float4*)(a.s[t] + j);
  const unsigned int lo = (unsigned int)f2bf(v.x) | ((unsigned int)f2bf(v.y) << 16);
  const unsigned int hi = (unsigned int)f2bf(v.z) | ((unsigned int)f2bf(v.w) << 16);
  *(uint2*)(a.d[t] + j) = make_uint2(lo, hi);
}

// ------------------------------------------------------------------
// bias concat: out[0:768)=q, [768:1536)=k, [1536:2304)=v  (f32)
// ------------------------------------------------------------------
__global__ __launch_bounds__(256) void biascat_kernel(
    const float* __restrict__ q, const float* __restrict__ k,
    const float* __restrict__ v, float* __restrict__ out)
{
  const int i = blockIdx.x * 256 + threadIdx.x;
  if (i >= 2304) return;
  float val;
  if (i < 768)        val = q[i];
  else if (i < 1536)  val = k[i - 768];
  else                val = v[i - 1536];
  out[i] = val;
}

// ------------------------------------------------------------------
// stage 1: wave-per-token embeddings + LN(256) x2 + pos projection
// ------------------------------------------------------------------
__global__ __launch_bounds__(256) void embed_kernel(
    const int* __restrict__ tids, const int* __restrict__ lids,
    const float* __restrict__ xs, const float* __restrict__ ys, const float* __restrict__ zs,
    const float* __restrict__ temb, const float* __restrict__ lemb,
    const float* __restrict__ tg, const float* __restrict__ tb,
    const float* __restrict__ lg, const float* __restrict__ lb,
    const float* __restrict__ pw, const float* __restrict__ pb,
    unsigned short* __restrict__ hb)
{
  const int tok = blockIdx.x * 4 + (threadIdx.x >> 6);
  const int lane = threadIdx.x & 63;
  const int e0 = lane * 4;
  const int ti = tids[tok], li = lids[tok];
  float4 tv = make_float4(0.f, 0.f, 0.f, 0.f);
  float4 lv = make_float4(0.f, 0.f, 0.f, 0.f);
  if (ti != 0) tv = *(const float4*)(temb + ti * 256 + e0);
  if (li != 0) lv = *(const float4*)(lemb + li * 256 + e0);

  float s0 = tv.x + tv.y + tv.z + tv.w;
  float s1 = tv.x * tv.x + tv.y * tv.y + tv.z * tv.z + tv.w * tv.w;
  float s2 = lv.x + lv.y + lv.z + lv.w;
  float s3 = lv.x * lv.x + lv.y * lv.y + lv.z * lv.z + lv.w * lv.w;
  #pragma unroll
  for (int off = 32; off > 0; off >>= 1) {
    s0 += __shfl_xor(s0, off, 64);
    s1 += __shfl_xor(s1, off, 64);
    s2 += __shfl_xor(s2, off, 64);
    s3 += __shfl_xor(s3, off, 64);
  }
  const float mt = s0 * (1.f / 256.f), vt = s1 * (1.f / 256.f) - mt * mt;
  const float ml = s2 * (1.f / 256.f), vl = s3 * (1.f / 256.f) - ml * ml;
  const float rt = rsqrtf(vt + 1e-5f), rl = rsqrtf(vl + 1e-5f);

  const float4 tg4 = *(const float4*)(tg + e0), tb4 = *(const float4*)(tb + e0);
  const float4 lg4 = *(const float4*)(lg + e0), lb4 = *(const float4*)(lb + e0);
  const size_t base = (size_t)tok * 768;
  ushort4 o;
  o.x = f2bf((tv.x - mt) * rt * tg4.x + tb4.x);
  o.y = f2bf((tv.y - mt) * rt * tg4.y + tb4.y);
  o.z = f2bf((tv.z - mt) * rt * tg4.z + tb4.z);
  o.w = f2bf((tv.w - mt) * rt * tg4.w + tb4.w);
  *(ushort4*)(hb + base + e0) = o;
  o.x = f2bf((lv.x - ml) * rl * lg4.x + lb4.x);
  o.y = f2bf((lv.y - ml) * rl * lg4.y + lb4.y);
  o.z = f2bf((lv.z - ml) * rl * lg4.z + lb4.z);
  o.w = f2bf((lv.w - ml) * rl * lg4.w + lb4.w);
  *(ushort4*)(hb + base + 256 + e0) = o;

  const float X = xs[tok], Y = ys[tok], Z = zs[tok];
  const float4 w0 = *(const float4*)(pw + 12 * lane);
  const float4 w1 = *(const float4*)(pw + 12 * lane + 4);
  const float4 w2 = *(const float4*)(pw + 12 * lane + 8);
  const float4 pb4 = *(const float4*)(pb + e0);
  o.x = f2bf(w0.x * X + w0.y * Y + w0.z * Z + pb4.x);
  o.y = f2bf(w0.w * X + w1.x * Y + w1.y * Z + pb4.y);
  o.z = f2bf(w1.z * X + w1.w * Y + w2.x * Z + pb4.z);
  o.w = f2bf(w2.y * X + w2.z * Y + w2.w * Z + pb4.w);
  *(ushort4*)(hb + base + 512 + e0) = o;
}

// ------------------------------------------------------------------
// LayerNorm, wave-per-row, D=768. XBF/RBF select input dtypes.
// ------------------------------------------------------------------
template<int XBF, int RBF>
__global__ __launch_bounds__(256) void ln_kernel(
    const void* __restrict__ x, const void* __restrict__ res,
    const float* __restrict__ g, const float* __restrict__ b,
    float* __restrict__ yf, unsigned short* __restrict__ yb,
    int nrows, float eps)
{
  const int row = blockIdx.x * 4 + (threadIdx.x >> 6);
  if (row >= nrows) return;
  const int lane = threadIdx.x & 63;
  const size_t base = (size_t)row * 768;
  const int e0 = lane * 12;
  float v[12];
  #pragma unroll
  for (int j = 0; j < 3; ++j) {
    if (XBF) {
      const ushort4 u = *(const ushort4*)((const unsigned short*)x + base + e0 + 4 * j);
      v[4*j+0] = bf2f(u.x); v[4*j+1] = bf2f(u.y); v[4*j+2] = bf2f(u.z); v[4*j+3] = bf2f(u.w);
    } else {
      const float4 f = *(const float4*)((const float*)x + base + e0 + 4 * j);
      v[4*j+0] = f.x; v[4*j+1] = f.y; v[4*j+2] = f.z; v[4*j+3] = f.w;
    }
  }
  if (res) {
    #pragma unroll
    for (int j = 0; j < 3; ++j) {
      if (RBF) {
        const ushort4 u = *(const ushort4*)((const unsigned short*)res + base + e0 + 4 * j);
        v[4*j+0] += bf2f(u.x); v[4*j+1] += bf2f(u.y); v[4*j+2] += bf2f(u.z); v[4*j+3] += bf2f(u.w);
      } else {
        const float4 f = *(const float4*)((const float*)res + base + e0 + 4 * j);
        v[4*j+0] += f.x; v[4*j+1] += f.y; v[4*j+2] += f.z; v[4*j+3] += f.w;
      }
    }
  }
  float s = 0.f, ss = 0.f;
  #pragma unroll
  for (int j = 0; j < 12; ++j) { s += v[j]; ss += v[j] * v[j]; }
  #pragma unroll
  for (int off = 32; off > 0; off >>= 1) {
    s += __shfl_xor(s, off, 64);
    ss += __shfl_xor(ss, off, 64);
  }
  const float mean = s * (1.f / 768.f);
  const float rstd = rsqrtf(ss * (1.f / 768.f) - mean * mean + eps);
  #pragma unroll
  for (int j = 0; j < 3; ++j) {
    const float4 g4 = *(const float4*)(g + e0 + 4 * j);
    const float4 b4 = *(const float4*)(b + e0 + 4 * j);
    float o0 = (v[4*j+0] - mean) * rstd * g4.x + b4.x;
    float o1 = (v[4*j+1] - mean) * rstd * g4.y + b4.y;
    float o2 = (v[4*j+2] - mean) * rstd * g4.z + b4.z;
    float o3 = (v[4*j+3] - mean) * rstd * g4.w + b4.w;
    if (yf) *(float4*)(yf + base + e0 + 4 * j) = make_float4(o0, o1, o2, o3);
    if (yb) {
      ushort4 u; u.x = f2bf(o0); u.y = f2bf(o1); u.z = f2bf(o2); u.w = f2bf(o3);
      *(ushort4*)(yb + base + e0 + 4 * j) = u;
    }
  }
}

// ------------------------------------------------------------------
// V transpose: v[b][k][rs-strided] (k<Lk) -> vt[b][d][128] zero-padded
// ------------------------------------------------------------------
__global__ __launch_bounds__(256) void vtrans_kernel(
    const unsigned short* __restrict__ v, unsigned short* __restrict__ vt,
    int Lk, int rs, long long sIn, long long sOut)
{
  __shared__ unsigned short s[64][132];
  const int b = blockIdx.y, d0 = blockIdx.x * 64;
  const unsigned short* vb = v + (long long)b * sIn;
  unsigned short* ob = vt + (long long)b * sOut;
  for (int idx = threadIdx.x; idx < 128 * 64; idx += 256) {
    const int k = idx >> 6, dd = idx & 63;
    s[dd][k] = (k < Lk) ? vb[(long long)k * rs + d0 + dd] : (unsigned short)0;
  }
  __syncthreads();
  for (int idx = threadIdx.x; idx < 64 * 128; idx += 256) {
    const int dd = idx >> 7, k = idx & 127;
    ob[(long long)(d0 + dd) * 128 + k] = s[dd][k];
  }
}

// ------------------------------------------------------------------
// stage-2 softmax, wave-per-row: rows [c][q<100], width 100 -> 128 pad
// ------------------------------------------------------------------
__global__ __launch_bounds__(256) void sm2_kernel(
    const float* __restrict__ P32, unsigned short* __restrict__ Pbf, int nrows)
{
  const int rid = blockIdx.x * 4 + (threadIdx.x >> 6);
  if (rid >= nrows) return;
  const int z = rid / 100, q = rid - z * 100;
  const int lane = threadIdx.x & 63;
  const float* row = P32 + (size_t)z * 16384 + (size_t)q * 128;
  unsigned short* orow = Pbf + (size_t)z * 16384 + (size_t)q * 128;
  const float v0 = row[lane];
  const float v1 = (lane + 64 < 100) ? row[lane + 64] : -3.4e38f;
  float m = fmaxf(v0, v1);
  #pragma unroll
  for (int off = 32; off > 0; off >>= 1) m = fmaxf(m, __shfl_xor(m, off, 64));
  const float e0 = expf(v0 - m);
  const float e1 = (lane + 64 < 100) ? expf(v1 - m) : 0.f;
  float s = e0 + e1;
  #pragma unroll
  for (int off = 32; off > 0; off >>= 1) s += __shfl_xor(s, off, 64);
  const float inv = 1.f / s;
  orow[lane] = f2bf(e0 * inv);
  orow[lane + 64] = (lane + 64 < 100) ? f2bf(e1 * inv) : (unsigned short)0;
}

// ------------------------------------------------------------------
// stage-3 masked deberta softmax, wave-per-row -> bf16 [8][128][128]
// ------------------------------------------------------------------
__global__ __launch_bounds__(256) void deb3_kernel(
    const float* __restrict__ sc,   // [8][128][128]
    const float* __restrict__ c2p,  // [640][512]
    const float* __restrict__ p2c,  // [640][512]
    const int* __restrict__ mask,   // [8][80][100]
    unsigned short* __restrict__ probs) // [8][128][128]
{
  const int rid = blockIdx.x * 4 + (threadIdx.x >> 6);
  if (rid >= 640) return;
  const int b = rid / 80, q = rid - b * 80;
  const int lane = threadIdx.x & 63;
  const bool mq = mask[(size_t)rid * 100] > 0;
  float v0 = -3.4e38f, v1 = -3.4e38f;
  bool val0 = false, val1 = false;
  {
    const int k = lane;            // k < 80 always
    const bool mk = mask[(size_t)(b * 80 + k) * 100] > 0;
    val0 = mq && mk;
    const int r = 256 + q - k;
    if (val0)
      v0 = sc[(size_t)b * 16384 + (size_t)q * 128 + k] +
           (c2p[(size_t)rid * 512 + r] + p2c[(size_t)(b * 80 + k) * 512 + r]) * (1.f / 48.f);
  }
  if (lane + 64 < 80) {
    const int k = lane + 64;
    const bool mk = mask[(size_t)(b * 80 + k) * 100] > 0;
    val1 = mq && mk;
    const int r = 256 + q - k;
    if (val1)
      v1 = sc[(size_t)b * 16384 + (size_t)q * 128 + k] +
           (c2p[(size_t)rid * 512 + r] + p2c[(size_t)(b * 80 + k) * 512 + r]) * (1.f / 48.f);
  }
  float m = fmaxf(v0, v1);
  #pragma unroll
  for (int off = 32; off > 0; off >>= 1) m = fmaxf(m, __shfl_xor(m, off, 64));
  const float e0 = val0 ? expf(v0 - m) : 0.f;
  const float e1 = val1 ? expf(v1 - m) : 0.f;
  float s = e0 + e1;
  #pragma unroll
  for (int off = 32; off > 0; off >>= 1) s += __shfl_xor(s, off, 64);
  const float inv = (s > 0.f) ? 1.f / s : 0.f;
  unsigned short* orow = probs + (size_t)b * 16384 + (size_t)q * 128;
  orow[lane] = val0 ? f2bf(e0 * inv) : (unsigned short)0;
  orow[lane + 64] = val1 ? f2bf(e1 * inv) : (unsigned short)0;
}

// ------------------------------------------------------------------
// means
// ------------------------------------------------------------------
__global__ __launch_bounds__(192) void meanL_kernel(
    const unsigned short* __restrict__ hb, float* __restrict__ hf,
    unsigned short* __restrict__ hfb)
{
  const int bf = blockIdx.x;            // 640
  const int d0 = threadIdx.x * 4;       // 0..764
  float4 acc = make_float4(0.f, 0.f, 0.f, 0.f);
  for (int l = 0; l < 100; ++l) {
    const ushort4 u = *(const ushort4*)(hb + ((size_t)bf * 100 + l) * 768 + d0);
    acc.x += bf2f(u.x); acc.y += bf2f(u.y); acc.z += bf2f(u.z); acc.w += bf2f(u.w);
  }
  acc.x *= 0.01f; acc.y *= 0.01f; acc.z *= 0.01f; acc.w *= 0.01f;
  *(float4*)(hf + (size_t)bf * 768 + d0) = acc;
  ushort4 o; o.x = f2bf(acc.x); o.y = f2bf(acc.y); o.z = f2bf(acc.z); o.w = f2bf(acc.w);
  *(ushort4*)(hfb + (size_t)bf * 768 + d0) = o;
}

__global__ __launch_bounds__(192) void meanF_kernel(const float* __restrict__ h4, float* __restrict__ hm)
{
  const int b = blockIdx.x;             // 8
  const int d0 = threadIdx.x * 4;
  float4 acc = make_float4(0.f, 0.f, 0.f, 0.f);
  for (int f = 0; f < 80; ++f) {
    const float4 u = *(const float4*)(h4 + ((size_t)b * 80 + f) * 768 + d0);
    acc.x += u.x; acc.y += u.y; acc.z += u.z; acc.w += u.w;
  }
  const float k = 1.f / 80.f;
  *(float4*)(hm + (size_t)b * 768 + d0) = make_float4(acc.x * k, acc.y * k, acc.z * k, acc.w * k);
}

// ------------------------------------------------------------------
// head: out[b][n] = hm[b] . head_w[n] + head_b[n]
// ------------------------------------------------------------------
__global__ __launch_bounds__(64) void head_kernel(
    const float* __restrict__ hm, const float* __restrict__ w,
    const float* __restrict__ bias, float* __restrict__ out)
{
  const int n = blockIdx.x, b = blockIdx.y;
  const float* x = hm + (size_t)b * 768;
  const float* wn = w + (size_t)n * 768;
  float s = 0.f;
  for (int i = threadIdx.x * 4; i < 768; i += 256) {
    const float4 xv = *(const float4*)(x + i);
    const float4 wv = *(const float4*)(wn + i);
    s += xv.x * wv.x + xv.y * wv.y + xv.z * wv.z + xv.w * wv.w;
  }
  #pragma unroll
  for (int off = 32; off > 0; off >>= 1) s += __shfl_down(s, off, 64);
  if (threadIdx.x == 0) out[(size_t)b * 250 + n] = s + bias[n];
}

// ------------------------------------------------------------------
// host
// ------------------------------------------------------------------
extern "C" void kernel_launch(void* const* d_in, const int* in_sizes, int n_in,
                              void* d_out, int out_size, void* d_ws, size_t ws_size,
                              hipStream_t stream)
{
  const int*   type_ids   = (const int*)  d_in[0];
  const int*   lm_ids     = (const int*)  d_in[1];
  const float* xs         = (const float*)d_in[2];
  const float* ys         = (const float*)d_in[3];
  const float* zs         = (const float*)d_in[4];
  const int*   mask       = (const int*)  d_in[5];
  const float* type_emb   = (const float*)d_in[6];
  const float* lm_emb     = (const float*)d_in[7];
  const float* type_ln_g  = (const float*)d_in[8];
  const float* type_ln_b  = (const float*)d_in[9];
  const float* lm_ln_g    = (const float*)d_in[10];
  const float* lm_ln_b    = (const float*)d_in[11];
  const float* pos_w      = (const float*)d_in[12];
  const float* pos_b      = (const float*)d_in[13];
  const float* lt_in_w    = (const float*)d_in[14];
  const float* lt_in_b    = (const float*)d_in[15];
  const float* lt_out_w   = (const float*)d_in[16];
  const float* lt_out_b   = (const float*)d_in[17];
  const float* lt_ln1_g   = (const float*)d_in[18];
  const float* lt_ln1_b   = (const float*)d_in[19];
  const float* lt_ff1_w   = (const float*)d_in[20];
  const float* lt_ff1_b   = (const float*)d_in[21];
  const float* lt_ff2_w   = (const float*)d_in[22];
  const float* lt_ff2_b   = (const float*)d_in[23];
  const float* lt_ln2_g   = (const float*)d_in[24];
  const float* lt_ln2_b   = (const float*)d_in[25];
  const float* rel_emb    = (const float*)d_in[26];
  const float* rel_ln_g   = (const float*)d_in[27];
  const float* rel_ln_b   = (const float*)d_in[28];
  const float* dq_w       = (const float*)d_in[29];
  const float* dq_b       = (const float*)d_in[30];
  const float* dk_w       = (const float*)d_in[31];
  const float* dk_b       = (const float*)d_in[32];
  const float* dv_w       = (const float*)d_in[33];
  const float* dv_b       = (const float*)d_in[34];
  const float* dao_w      = (const float*)d_in[35];
  const float* dao_b      = (const float*)d_in[36];
  const float* da_ln_g    = (const float*)d_in[37];
  const float* da_ln_b    = (const float*)d_in[38];
  const float* di_w       = (const float*)d_in[39];
  const float* di_b       = (const float*)d_in[40];
  const float* do_w       = (const float*)d_in[41];
  const float* do_b       = (const float*)d_in[42];
  const float* do_ln_g    = (const float*)d_in[43];
  const float* do_ln_b    = (const float*)d_in[44];
  const float* head_w     = (const float*)d_in[45];
  const float* head_b     = (const float*)d_in[46];
  float* out = (float*)d_out;
  float* ws  = (float*)d_ws;

  const float inv_sqrt_d = 0.03608439182435161f;  // 1/sqrt(768)
  const long long W2 = 768 * 768;

  auto rnd = [](size_t x) { return (x + 63) & ~(size_t)63; };
  const size_t ws_floats = ws_size / sizeof(float);

  // ---- persistent region (float units) ----
  size_t o = 0;
  const size_t offHB = o; o += rnd((size_t)64000 * 768 / 2);   // h bf16
  auto woff = [&](size_t elems) { size_t r = o; o += rnd(elems / 2); return r; };
  const size_t w_in   = woff((size_t)2304 * 768);
  const size_t w_out  = woff((size_t)768 * 768);
  const size_t w_f1   = woff((size_t)768 * 768);
  const size_t w_f2   = woff((size_t)768 * 768);
  const size_t w_qkv3 = woff((size_t)2304 * 768);   // dq|dk|dv
  const size_t w_ao   = woff((size_t)768 * 768);
  const size_t w_di   = woff((size_t)3072 * 768);
  const size_t w_do   = woff((size_t)768 * 3072);
  const size_t b_qkv3 = o; o += rnd(2304);          // f32 concat bias
  const size_t scratch0 = o;

  // ---- stage-3 scratch need ----
  size_t s3need = 0;
  {
    size_t t = 0;
    t += rnd((size_t)640 * 768);         // hf f32
    t += rnd((size_t)640 * 768 / 2);     // hfb
    t += rnd((size_t)640 * 2304 / 2);    // qkv3b
    t += rnd((size_t)512 * 768 / 2);     // rlnb
    t += rnd((size_t)512 * 1536 / 2);    // posb
    t += 2 * (size_t)640 * 512;          // c2p,p2c f32 (contiguous)
    t += rnd((size_t)8 * 16384);         // p32_3
    t += rnd((size_t)8 * 16384 / 2);     // p3bf
    t += rnd((size_t)8 * 98304 / 2);     // vt3
    t += rnd((size_t)640 * 768 / 2);     // ctx3b
    t += 2 * rnd((size_t)640 * 768);     // t3,h3
    t += rnd((size_t)640 * 768 / 2);     // h3b
    t += rnd((size_t)640 * 3072 / 2);    // interb
    t += 2 * rnd((size_t)640 * 768);     // t4,h4
    t += rnd((size_t)8 * 768);           // hm
    s3need = t;
  }

  // ---- pick stage-2 chunk size (all bf16 intermediates) ----
  auto chunk_need = [&](int c) {
    const size_t R = (size_t)c * 100;
    size_t t = 0;
    t += rnd(R * 2304 / 2);             // qkv
    t += 4 * rnd(R * 768 / 2);          // ctx, t1b, h1b, ffo
    t += rnd((size_t)c * 98304 / 2);    // vt
    t += rnd((size_t)c * 16384);        // p32 f32
    t += rnd((size_t)c * 16384 / 2);    // pbf
    return t;
  };
  int C = 1;
  {
    const int cands[] = {640, 320, 160, 80, 40, 20, 10, 5, 2, 1};
    for (int c : cands) {
      const size_t need = scratch0 + (chunk_need(c) > s3need ? chunk_need(c) : s3need);
      if (need <= ws_floats) { C = c; break; }
    }
  }
  const size_t R = (size_t)C * 100;

  // stage-2 chunk layout
  o = scratch0;
  const size_t qkvb = o; o += rnd(R * 2304 / 2);
  const size_t ctxb = o; o += rnd(R * 768 / 2);
  const size_t t1b  = o; o += rnd(R * 768 / 2);
  const size_t h1bb = o; o += rnd(R * 768 / 2);
  const size_t ffob = o; o += rnd(R * 768 / 2);
  const size_t vtb  = o; o += rnd((size_t)C * 98304 / 2);
  const size_t p32  = o; o += rnd((size_t)C * 16384);
  const size_t pbf  = o; o += rnd((size_t)C * 16384 / 2);

  auto US = [&](size_t foff) { return (unsigned short*)(ws + foff); };

  // ---------------- fused weight conversion ----------------
  {
    ConvArgs a;
    const float* srcs[10] = {lt_in_w, lt_out_w, lt_ff1_w, lt_ff2_w,
                             dq_w, dk_w, dv_w, dao_w, di_w, do_w};
    unsigned short* dsts[10] = {US(w_in), US(w_out), US(w_f1), US(w_f2),
                                US(w_qkv3), US(w_qkv3) + W2, US(w_qkv3) + 2 * W2,
                                US(w_ao), US(w_di), US(w_do)};
    const long long ns[10] = {2304 * 768, W2, W2, W2, W2, W2, W2, W2,
                              3072 * 768, 3072 * 768};
    long long tot = 0;
    for (int i = 0; i < 10; ++i) { a.s[i] = srcs[i]; a.d[i] = dsts[i]; a.off[i] = tot; tot += ns[i]; }
    a.off[10] = tot;
    convall_kernel<<<(unsigned)((tot / 4 + 255) / 256), 256, 0, stream>>>(a, tot);
  }
  // concat deberta qkv bias (f32) -- single kernel, replaces 3 memcpy nodes
  biascat_kernel<<<9, 256, 0, stream>>>(dq_b, dk_b, dv_b, ws + b_qkv3);

  // ---------------- stage 1 ----------------
  embed_kernel<<<16000, 256, 0, stream>>>(type_ids, lm_ids, xs, ys, zs,
      type_emb, lm_emb, type_ln_g, type_ln_b, lm_ln_g, lm_ln_b, pos_w, pos_b,
      US(offHB));

  // ---------------- stage 2 (chunked over sequences) ----------------
  for (int c0 = 0; c0 < 640; c0 += C) {
    unsigned short* hbc = US(offHB) + (size_t)c0 * 100 * 768;
    const int Rr = C * 100;
    // fused qkv
    mgemm(stream, 0, true, hbc, US(w_in), lt_in_b, US(qkvb),
          Rr, 2304, 768, 768, 768, 2304, 0, 0, 0, 0, 1, 1.f);
    // scores, batched per sequence
    mgemm(stream, 0, false, US(qkvb), US(qkvb) + 768, nullptr, ws + p32,
          100, 100, 768, 2304, 2304, 128, 230400, 230400, 16384, 0, C, inv_sqrt_d);
    sm2_kernel<<<(Rr + 3) / 4, 256, 0, stream>>>(ws + p32, US(pbf), Rr);
    vtrans_kernel<<<dim3(12, C), 256, 0, stream>>>(US(qkvb) + 1536, US(vtb), 100, 2304, 230400, 98304);
    mgemm(stream, 0, true, US(pbf), US(vtb), nullptr, US(ctxb),
          100, 768, 128, 128, 128, 768, 16384, 98304, 76800, 0, C, 1.f);
    // out projection (bf16)
    mgemm(stream, 0, true, US(ctxb), US(w_out), lt_out_b, US(t1b),
          Rr, 768, 768, 768, 768, 768, 0, 0, 0, 0, 1, 1.f);
    // h1 = LN(h + attn)
    ln_kernel<1, 1><<<(Rr + 3) / 4, 256, 0, stream>>>(hbc, US(t1b),
        lt_ln1_g, lt_ln1_b, nullptr, US(h1bb), Rr, 1e-5f);
    // ff
    mgemm(stream, 1, true, US(h1bb), US(w_f1), lt_ff1_b, US(ffob),
          Rr, 768, 768, 768, 768, 768, 0, 0, 0, 0, 1, 1.f);
    mgemm(stream, 0, true, US(ffob), US(w_f2), lt_ff2_b, US(t1b),
          Rr, 768, 768, 768, 768, 768, 0, 0, 0, 0, 1, 1.f);
    // h2 = LN(h1 + ff) -> back into h
    ln_kernel<1, 1><<<(Rr + 3) / 4, 256, 0, stream>>>(US(h1bb), US(t1b),
        lt_ln2_g, lt_ln2_b, nullptr, hbc, Rr, 1e-5f);
  }

  // ---------------- stage 3 layout ----------------
  o = scratch0;
  const size_t hf    = o; o += rnd((size_t)640 * 768);
  const size_t hfb   = o; o += rnd((size_t)640 * 768 / 2);
  const size_t qkv3b = o; o += rnd((size_t)640 * 2304 / 2);
  const size_t rlnb  = o; o += rnd((size_t)512 * 768 / 2);
  const size_t posb  = o; o += rnd((size_t)512 * 1536 / 2);
  const size_t c2p   = o; o += (size_t)640 * 512;
  const size_t p2c   = o; o += (size_t)640 * 512;
  const size_t p32_3 = o; o += rnd((size_t)8 * 16384);
  const size_t p3bf  = o; o += rnd((size_t)8 * 16384 / 2);
  const size_t vt3b  = o; o += rnd((size_t)8 * 98304 / 2);
  const size_t ctx3b = o; o += rnd((size_t)640 * 768 / 2);
  const size_t t3    = o; o += rnd((size_t)640 * 768);
  const size_t h3    = o; o += rnd((size_t)640 * 768);
  const size_t h3b   = o; o += rnd((size_t)640 * 768 / 2);
  const size_t interb= o; o += rnd((size_t)640 * 3072 / 2);
  const size_t t4    = o; o += rnd((size_t)640 * 768);
  const size_t h4    = o; o += rnd((size_t)640 * 768);
  const size_t hm    = o; o += rnd((size_t)8 * 768);

  meanL_kernel<<<640, 192, 0, stream>>>(US(offHB), ws + hf, US(hfb));
  // fused q|k|v projection
  mgemm(stream, 0, true, US(hfb), US(w_qkv3), ws + b_qkv3, US(qkv3b),
        640, 2304, 768, 768, 768, 2304, 0, 0, 0, 0, 1, 1.f);
  // rel embedding LN
  ln_kernel<0, 0><<<128, 256, 0, stream>>>(rel_emb, nullptr,
      rel_ln_g, rel_ln_b, nullptr, US(rlnb), 512, 1e-7f);
  // pos_k | pos_q (batched; z=0 uses dk, z=1 uses dq)
  mgemm(stream, 0, true, US(rlnb), US(w_qkv3) + W2, ws + b_qkv3 + 768, US(posb),
        512, 768, 768, 768, 768, 1536, 0, -W2, 768, -768, 2, 1.f);
  // content scores /48, batched over B=8
  mgemm(stream, 0, false, US(qkv3b), US(qkv3b) + 768, nullptr, ws + p32_3,
        80, 80, 768, 2304, 2304, 128, 184320, 184320, 16384, 0, 8, 1.f / 48.f);
  // c2p (q @ pos_k^T) and p2c (k @ pos_q^T), batched
  mgemm(stream, 0, false, US(qkv3b), US(posb), nullptr, ws + c2p,
        640, 512, 768, 2304, 1536, 512, 768, 768, 327680, 0, 2, 1.f);
  // masked softmax -> bf16 probs
  deb3_kernel<<<160, 256, 0, stream>>>(ws + p32_3, ws + c2p, ws + p2c, mask, US(p3bf));
  // ctx = P @ V
  vtrans_kernel<<<dim3(12, 8), 256, 0, stream>>>(US(qkv3b) + 1536, US(vt3b), 80, 2304, 184320, 98304);
  mgemm(stream, 0, true, US(p3bf), US(vt3b), nullptr, US(ctx3b),
        80, 768, 128, 128, 128, 768, 16384, 98304, 61440, 0, 8, 1.f);
  // attention output + LN
  mgemm(stream, 0, false, US(ctx3b), US(w_ao), dao_b, ws + t3,
        640, 768, 768, 768, 768, 768, 0, 0, 0, 0, 1, 1.f);
  ln_kernel<0, 0><<<160, 256, 0, stream>>>(ws + hf, ws + t3,
      da_ln_g, da_ln_b, ws + h3, US(h3b), 640, 1e-7f);
  // FFN (exact gelu) + LN
  mgemm(stream, 2, true, US(h3b), US(w_di), di_b, US(interb),
        640, 3072, 768, 768, 768, 3072, 0, 0, 0, 0, 1, 1.f);
  mgemm(stream, 0, false, US(interb), US(w_do), do_b, ws + t4,
        640, 768, 3072, 3072, 3072, 768, 0, 0, 0, 0, 1, 1.f);
  ln_kernel<0, 0><<<160, 256, 0, stream>>>(ws + h3, ws + t4,
      do_ln_g, do_ln_b, ws + h4, nullptr, 640, 1e-7f);
  // mean over frames + head
  meanF_kernel<<<8, 192, 0, stream>>>(ws + h4, ws + hm);
  head_kernel<<<dim3(250, 8), 64, 0, stream>>>(ws + hm, head_w, head_b, out);
}